// Round 2
// baseline (1572.377 us; speedup 1.0000x reference)
//
#include <hip/hip_runtime.h>
#include <hip/hip_bf16.h>

// DIEN (DIN_V2_Gru_Vec_attGru) forward. B=512, T=200, D=128, H=128.
// Chunked pipeline (NC=4 chunks of TC=50 steps) to keep workspace ~94 MB:
//  prep_weights : bf16-transpose/pad weights, padded biases
//  cast_his_t   : item_his_eb f32 [B,T,D] -> bf16 t-major [T,B,D]
//  per chunk    : gemm xproj (bf16 MFMA, f32 out) ; gru_chunk (sequential, f32)
//  per chunk    : build_din ; att gemm1(sig) ; att gemm2(sig) ; scorer
//  softmax      : masked softmax over scores -> alphas
//  per chunk    : gemm xproj2 ; augru_chunk
//  feat + head  : f32

typedef __attribute__((ext_vector_type(8))) short bf16x8;
typedef __attribute__((ext_vector_type(4))) float f32x4;

#define NC 4
#define TC 50

static __device__ __forceinline__ unsigned short f2bf(float f) {
  union { __hip_bfloat16 h; unsigned short u; } v;
  v.h = __float2bfloat16(f);
  return v.u;
}
static __device__ __forceinline__ float bf2f(unsigned short u) {
  union { __hip_bfloat16 h; unsigned short u; } v;
  v.u = u;
  return __bfloat162float(v.h);
}

// ---------------------------------------------------------------- prep
__global__ __launch_bounds__(256) void prep_weights(
    const float* __restrict__ Wg1, const float* __restrict__ Wc1,
    const float* __restrict__ Wg2, const float* __restrict__ Wc2,
    const float* __restrict__ aw1, const float* __restrict__ aw2,
    const float* __restrict__ bg1, const float* __restrict__ bc1,
    const float* __restrict__ bg2, const float* __restrict__ bc2,
    const float* __restrict__ ab1, const float* __restrict__ ab2,
    unsigned short* __restrict__ W1xT, unsigned short* __restrict__ W2xT,
    unsigned short* __restrict__ AW1T, unsigned short* __restrict__ AW2T,
    float* __restrict__ b384_1, float* __restrict__ b384_2,
    float* __restrict__ bA1, float* __restrict__ bA2)
{
  int e = blockIdx.x * 256 + threadIdx.x;
  if (e < 49152) {              // W1xT/W2xT: [384 n][128 k]; n<256 from Wg, else Wc
    int n = e >> 7, k = e & 127;
    float v1 = (n < 256) ? Wg1[k * 256 + n] : Wc1[k * 128 + (n - 256)];
    float v2 = (n < 256) ? Wg2[k * 256 + n] : Wc2[k * 128 + (n - 256)];
    W1xT[e] = f2bf(v1);
    W2xT[e] = f2bf(v2);
  }
  if (e < 65536) {              // AW1T: [128 n][512 k], pad n>=80 with 0
    int n = e >> 9, k = e & 511;
    AW1T[e] = f2bf(n < 80 ? aw1[k * 80 + n] : 0.f);
  }
  if (e < 16384) {              // AW2T: [128 n][128 k], valid n<40 && k<80
    int n = e >> 7, k = e & 127;
    AW2T[e] = f2bf((n < 40 && k < 80) ? aw2[k * 40 + n] : 0.f);
  }
  if (e < 384) {
    b384_1[e] = (e < 256) ? bg1[e] : bc1[e - 256];
    b384_2[e] = (e < 256) ? bg2[e] : bc2[e - 256];
  }
  if (e < 128) {
    bA1[e] = (e < 80) ? ab1[e] : 0.f;
    bA2[e] = (e < 40) ? ab2[e] : 0.f;
  }
}

__global__ __launch_bounds__(256) void zero_f(float* __restrict__ p, int n) {
  int i = blockIdx.x * 256 + threadIdx.x;
  if (i < n) p[i] = 0.f;
}

// ---------------------------------------------------------------- cast his -> bf16 t-major
__global__ __launch_bounds__(256) void cast_his_t(const float4* __restrict__ in4,
                                                  ushort4* __restrict__ out4)
{
  int i = blockIdx.x * 256 + threadIdx.x;   // 3,276,800 total
  float4 v = in4[i];
  int d4 = (i & 31) << 2;
  int bt = i >> 5;
  int tt = bt % 200, bb = bt / 200;
  out4[(((size_t)tt * 512 + bb) * 128 + d4) >> 2] =
      make_ushort4(f2bf(v.x), f2bf(v.y), f2bf(v.z), f2bf(v.w));
}

// ---------------------------------------------------------------- bf16 MFMA GEMM
// C[M][N] = A[M][K] @ BT[N][K]^T (+bias). 128x128 tile, 256 thr, 4 waves.
// EPI 0: f32 out. EPI 1: bf16 out with sigmoid.
template <int EPI>
__global__ __launch_bounds__(256) void gemm_bt(
    const unsigned short* __restrict__ A, const unsigned short* __restrict__ BT,
    const float* __restrict__ bias, float* __restrict__ Cf,
    unsigned short* __restrict__ Cb, int K, int ldc)
{
  __shared__ uint4 AsB[1024];   // 128 rows x 64 bf16, xor-swizzled 16B chunks
  __shared__ uint4 BsB[1024];
  const int tid = threadIdx.x;
  const int w = tid >> 6, l = tid & 63;
  const long mBase = (long)blockIdx.x * 128;
  const int nBase = blockIdx.y * 128;

  f32x4 acc[2][8];
#pragma unroll
  for (int m = 0; m < 2; m++)
#pragma unroll
    for (int n = 0; n < 8; n++) acc[m][n] = 0.f;

  const int srow = (tid >> 3) & 31;
  const int scc = l & 7;

  for (int kb = 0; kb < K; kb += 64) {
#pragma unroll
    for (int p = 0; p < 4; p++) {
      int row = p * 32 + srow;
      uint4 va = *(const uint4*)(A + (size_t)(mBase + row) * K + kb + scc * 8);
      uint4 vb = *(const uint4*)(BT + (size_t)(nBase + row) * K + kb + scc * 8);
      AsB[row * 8 + (scc ^ (row & 7))] = va;
      BsB[row * 8 + (scc ^ (row & 7))] = vb;
    }
    __syncthreads();
#pragma unroll
    for (int ks = 0; ks < 2; ks++) {
      int ccr = ks * 4 + (l >> 4);
      int r0 = w * 32 + (l & 15);
      int r1 = r0 + 16;
      bf16x8 a0 = *(const bf16x8*)&AsB[r0 * 8 + (ccr ^ (r0 & 7))];
      bf16x8 a1 = *(const bf16x8*)&AsB[r1 * 8 + (ccr ^ (r1 & 7))];
#pragma unroll
      for (int n = 0; n < 8; n++) {
        int rb = n * 16 + (l & 15);
        bf16x8 bn = *(const bf16x8*)&BsB[rb * 8 + (ccr ^ (rb & 7))];
        acc[0][n] = __builtin_amdgcn_mfma_f32_16x16x32_bf16(a0, bn, acc[0][n], 0, 0, 0);
        acc[1][n] = __builtin_amdgcn_mfma_f32_16x16x32_bf16(a1, bn, acc[1][n], 0, 0, 0);
      }
    }
    __syncthreads();
  }

  const int lcol = l & 15, lrow4 = (l >> 4) * 4;
#pragma unroll
  for (int n = 0; n < 8; n++) {
    int gcol = nBase + n * 16 + lcol;
    float bb = bias[gcol];
#pragma unroll
    for (int m = 0; m < 2; m++) {
#pragma unroll
      for (int i = 0; i < 4; i++) {
        long grow = mBase + w * 32 + m * 16 + lrow4 + i;
        float v = acc[m][n][i] + bb;
        if (EPI == 0) {
          Cf[grow * ldc + gcol] = v;
        } else {
          Cb[grow * ldc + gcol] = f2bf(1.f / (1.f + __expf(-v)));
        }
      }
    }
  }
}

// ---------------------------------------------------------------- sequential GRU / AUGRU chunk
// 256 blocks x 2 batch rows, 512 threads. h-part weights in VGPRs.
// gates: thread t -> col jg=t>>1, k-half hg=t&1 (64 w regs)
// cand : thread t -> col jc=t>>2, k-quarter qc=t&3 (32 w regs)
// xproj chunk is t-major: row (t'*512 + b), 384 cols (256 gate | 128 cand preact).
template <int AUGRU>
__global__ __launch_bounds__(512) void gru_chunk(
    const float* __restrict__ xproj,
    const float* __restrict__ Wg,      // [256][256], rows 128.. = h part
    const float* __restrict__ Wc,      // [256][128], rows 128.. = h part
    const int* __restrict__ seqlen,
    const float* __restrict__ alphas,  // [B][T] (AUGRU only)
    unsigned short* __restrict__ outbf,// [T][B][128] bf16 full (GRU1 only)
    float* __restrict__ hstate,        // [B][128] f32 in/out
    int tbase)
{
  const int t = threadIdx.x;
  const int r0 = blockIdx.x * 2, r1 = r0 + 1;
  const int jg = t >> 1, hg = t & 1;
  const int jc = t >> 2, qc = t & 3;

  float wg[64], wc[32];
#pragma unroll
  for (int i = 0; i < 64; i++) wg[i] = Wg[(128 + hg * 64 + i) * 256 + jg];
#pragma unroll
  for (int i = 0; i < 32; i++) wc[i] = Wc[(128 + qc * 32 + i) * 128 + jc];

  __shared__ __align__(16) float hI[32][2][4];    // h, quad-interleaved
  __shared__ __align__(16) float rghI[32][2][4];  // rg*h
  __shared__ float uS[2][128];
  if (t < 256)
    ((float*)hI)[t] = hstate[(size_t)(r0 + ((t >> 2) & 1)) * 128 + (t >> 3) * 4 + (t & 3)];
  const int len0 = seqlen[r0], len1 = seqlen[r1];
  __syncthreads();

  for (int ts = 0; ts < TC; ++ts) {
    const float* xr0 = xproj + ((size_t)ts * 512 + r0) * 384;
    const float* xr1 = xproj + ((size_t)ts * 512 + r1) * 384;
    const int tg = tbase + ts;
    // ---- gates
    float xg0 = xr0[jg];
    float xg1 = xr1[jg];
    float a0 = 0.f, a1 = 0.f, a0b = 0.f, a1b = 0.f;
#pragma unroll
    for (int q = 0; q < 16; q += 2) {
      float4 h0 = *(const float4*)&hI[hg * 16 + q][0][0];
      float4 h1 = *(const float4*)&hI[hg * 16 + q][1][0];
      a0 += h0.x * wg[4 * q] + h0.y * wg[4 * q + 1] + h0.z * wg[4 * q + 2] + h0.w * wg[4 * q + 3];
      a1 += h1.x * wg[4 * q] + h1.y * wg[4 * q + 1] + h1.z * wg[4 * q + 2] + h1.w * wg[4 * q + 3];
      float4 h0b = *(const float4*)&hI[hg * 16 + q + 1][0][0];
      float4 h1b = *(const float4*)&hI[hg * 16 + q + 1][1][0];
      a0b += h0b.x * wg[4 * q + 4] + h0b.y * wg[4 * q + 5] + h0b.z * wg[4 * q + 6] + h0b.w * wg[4 * q + 7];
      a1b += h1b.x * wg[4 * q + 4] + h1b.y * wg[4 * q + 5] + h1b.z * wg[4 * q + 6] + h1b.w * wg[4 * q + 7];
    }
    a0 += a0b; a1 += a1b;
    a0 += __shfl_xor(a0, 1);
    a1 += __shfl_xor(a1, 1);
    a0 += xg0; a1 += xg1;
    float g0 = 1.f / (1.f + __expf(-a0));
    float g1 = 1.f / (1.f + __expf(-a1));
    if (hg == 0) {
      if (jg < 128) {
        rghI[jg >> 2][0][jg & 3] = g0 * hI[jg >> 2][0][jg & 3];
        rghI[jg >> 2][1][jg & 3] = g1 * hI[jg >> 2][1][jg & 3];
      } else {
        uS[0][jg - 128] = g0;
        uS[1][jg - 128] = g1;
      }
    }
    __syncthreads();
    // ---- candidate
    float c0 = 0.f, c1 = 0.f;
#pragma unroll
    for (int q = 0; q < 8; q++) {
      float4 v0 = *(const float4*)&rghI[qc * 8 + q][0][0];
      float4 v1 = *(const float4*)&rghI[qc * 8 + q][1][0];
      c0 += v0.x * wc[4 * q] + v0.y * wc[4 * q + 1] + v0.z * wc[4 * q + 2] + v0.w * wc[4 * q + 3];
      c1 += v1.x * wc[4 * q] + v1.y * wc[4 * q + 1] + v1.z * wc[4 * q + 2] + v1.w * wc[4 * q + 3];
    }
    c0 += __shfl_xor(c0, 1); c0 += __shfl_xor(c0, 2);
    c1 += __shfl_xor(c1, 1); c1 += __shfl_xor(c1, 2);
    c0 = tanhf(c0 + xr0[256 + jc]);
    c1 = tanhf(c1 + xr1[256 + jc]);
    float u0 = uS[0][jc], u1 = uS[1][jc];
    if (AUGRU) {
      u0 *= (1.f - alphas[r0 * 200 + tg]);
      u1 *= (1.f - alphas[r1 * 200 + tg]);
    }
    float h0 = hI[jc >> 2][0][jc & 3], h1v = hI[jc >> 2][1][jc & 3];
    float hn0 = u0 * h0 + (1.f - u0) * c0;
    float hn1 = u1 * h1v + (1.f - u1) * c1;
    bool v0 = tg < len0, v1 = tg < len1;
    hn0 = v0 ? hn0 : h0;
    hn1 = v1 ? hn1 : h1v;
    __syncthreads();
    if (qc == 0) {
      hI[jc >> 2][0][jc & 3] = hn0;
      hI[jc >> 2][1][jc & 3] = hn1;
      if (!AUGRU) {
        outbf[((size_t)tg * 512 + r0) * 128 + jc] = f2bf(v0 ? hn0 : 0.f);
        outbf[((size_t)tg * 512 + r1) * 128 + jc] = f2bf(v1 ? hn1 : 0.f);
      }
    }
    __syncthreads();
  }
  if (t < 256)
    hstate[(size_t)(r0 + ((t >> 2) & 1)) * 128 + (t >> 3) * 4 + (t & 3)] = ((float*)hI)[t];
}

// ---------------------------------------------------------------- din build (per chunk)
__global__ __launch_bounds__(256) void build_din(
    const float* __restrict__ item_eb, const unsigned short* __restrict__ rnn1bf,
    ushort4* __restrict__ din, int rowbase)
{
  int i = blockIdx.x * 256 + threadIdx.x;   // TC*512*32 threads, 4 cols each
  int r = i >> 5;                           // row within chunk (t-major: t'*512+b)
  int d4 = (i & 31) << 2;
  int b = r & 511;
  float4 q = *(const float4*)(item_eb + b * 128 + d4);
  const unsigned short* rp = rnn1bf + ((size_t)rowbase + r) * 128 + d4;
  unsigned short s0 = rp[0], s1 = rp[1], s2 = rp[2], s3 = rp[3];
  float r0 = bf2f(s0), r1 = bf2f(s1), r2 = bf2f(s2), r3 = bf2f(s3);
  size_t base = (size_t)r * 512 + d4;
  din[(base + 0) >> 2]   = make_ushort4(f2bf(q.x), f2bf(q.y), f2bf(q.z), f2bf(q.w));
  din[(base + 128) >> 2] = make_ushort4(s0, s1, s2, s3);
  din[(base + 256) >> 2] = make_ushort4(f2bf(q.x - r0), f2bf(q.y - r1), f2bf(q.z - r2), f2bf(q.w - r3));
  din[(base + 384) >> 2] = make_ushort4(f2bf(q.x * r0), f2bf(q.y * r1), f2bf(q.z * r2), f2bf(q.w * r3));
}

// ---------------------------------------------------------------- scorer (per chunk)
__global__ __launch_bounds__(256) void scorer(
    const unsigned short* __restrict__ h2, const float* __restrict__ w3,
    const float* __restrict__ b3, float* __restrict__ scores, int tbase)
{
  int r = blockIdx.x * 256 + threadIdx.x;   // [0, TC*512)
  int b = r & 511, tp = r >> 9;
  const unsigned short* row = h2 + (size_t)r * 128;
  float acc = b3[0];
#pragma unroll 8
  for (int k = 0; k < 40; k++) acc += bf2f(row[k]) * w3[k];
  scores[b * 200 + tbase + tp] = acc;
}

// ---------------------------------------------------------------- masked softmax
__global__ __launch_bounds__(256) void mask_softmax(
    const float* __restrict__ scores, const int* __restrict__ seqlen,
    float* __restrict__ alphas)
{
  int b = blockIdx.x, t = threadIdx.x;
  __shared__ float red[256];
  int len = seqlen[b];
  float s = (t < 200 && t < len) ? scores[b * 200 + t] : -1e30f;
  red[t] = s;
  __syncthreads();
  for (int o = 128; o > 0; o >>= 1) {
    if (t < o) red[t] = fmaxf(red[t], red[t + o]);
    __syncthreads();
  }
  float m = red[0];
  __syncthreads();
  float e = (t < 200 && t < len) ? __expf(s - m) : 0.f;
  red[t] = e;
  __syncthreads();
  for (int o = 128; o > 0; o >>= 1) {
    if (t < o) red[t] += red[t + o];
    __syncthreads();
  }
  float denom = red[0];
  if (t < 200) alphas[b * 200 + t] = e / denom;
}

// ---------------------------------------------------------------- his_sum + feat (f32)
__global__ __launch_bounds__(128) void feat_kernel(
    const float* __restrict__ item_eb, const float* __restrict__ his,
    const int* __restrict__ seqlen, const float* __restrict__ hT,
    float* __restrict__ feat)
{
  int b = blockIdx.x, d = threadIdx.x;
  int len = seqlen[b];
  float s = 0.f;
  const float* hp = his + (size_t)b * 200 * 128 + d;
  for (int ts = 0; ts < len; ++ts) s += hp[ts * 128];
  float q = item_eb[b * 128 + d];
  feat[b * 512 + d] = q;
  feat[b * 512 + 128 + d] = s;
  feat[b * 512 + 256 + d] = q * s;
  feat[b * 512 + 384 + d] = hT[b * 128 + d];
}

// ---------------------------------------------------------------- f32 head
__global__ __launch_bounds__(256) void head_kernel(
    const float* __restrict__ feat,
    const float* __restrict__ w1, const float* __restrict__ b1, const float* __restrict__ a1,
    const float* __restrict__ w2, const float* __restrict__ b2, const float* __restrict__ a2,
    const float* __restrict__ w3, const float* __restrict__ b3,
    float* __restrict__ out)
{
  int b = blockIdx.x, t = threadIdx.x;
  __shared__ float frow[512];
  __shared__ float z1[200];
  __shared__ float z2[80];
  frow[t] = feat[b * 512 + t];
  frow[256 + t] = feat[b * 512 + 256 + t];
  __syncthreads();
  if (t < 200) {
    float acc = b1[t];
#pragma unroll 8
    for (int k = 0; k < 512; k++) acc += frow[k] * w1[k * 200 + t];
    z1[t] = acc > 0.f ? acc : a1[t] * acc;
  }
  __syncthreads();
  if (t < 80) {
    float acc = b2[t];
#pragma unroll 8
    for (int k = 0; k < 200; k++) acc += z1[k] * w2[k * 80 + t];
    z2[t] = acc > 0.f ? acc : a2[t] * acc;
  }
  __syncthreads();
  if (t == 0) {
    float l0 = b3[0], l1 = b3[1];
    for (int k = 0; k < 80; k++) {
      float z = z2[k];
      l0 += z * w3[k * 2];
      l1 += z * w3[k * 2 + 1];
    }
    float m = fmaxf(l0, l1);
    float e0 = __expf(l0 - m), e1 = __expf(l1 - m);
    out[b * 2 + 0] = e0 / (e0 + e1);
    out[b * 2 + 1] = e1 / (e0 + e1);
  }
}

// ---------------------------------------------------------------- launch
extern "C" void kernel_launch(void* const* d_in, const int* in_sizes, int n_in,
                              void* d_out, int out_size, void* d_ws, size_t ws_size,
                              hipStream_t stream)
{
  const float* item_eb = (const float*)d_in[0];
  const float* his     = (const float*)d_in[1];
  const float* Wg1     = (const float*)d_in[2];
  const float* bg1     = (const float*)d_in[3];
  const float* Wc1     = (const float*)d_in[4];
  const float* bc1     = (const float*)d_in[5];
  const float* aw1     = (const float*)d_in[6];
  const float* ab1     = (const float*)d_in[7];
  const float* aw2     = (const float*)d_in[8];
  const float* ab2     = (const float*)d_in[9];
  const float* aw3     = (const float*)d_in[10];
  const float* ab3     = (const float*)d_in[11];
  const float* Wg2     = (const float*)d_in[12];
  const float* bg2     = (const float*)d_in[13];
  const float* Wc2     = (const float*)d_in[14];
  const float* bc2     = (const float*)d_in[15];
  const float* fc1w    = (const float*)d_in[16];
  const float* fc1b    = (const float*)d_in[17];
  const float* al1     = (const float*)d_in[18];
  const float* fc2w    = (const float*)d_in[19];
  const float* fc2b    = (const float*)d_in[20];
  const float* al2     = (const float*)d_in[21];
  const float* fc3w    = (const float*)d_in[22];
  const float* fc3b    = (const float*)d_in[23];
  const int*   seqlen  = (const int*)d_in[24];

  // ---- workspace layout (~94.3 MB peak, regions reused across phases)
  char* ws = (char*)d_ws;
  unsigned short* XhA    = (unsigned short*)(ws + 0L);           // 26,214,400: Xh_t, later din chunk
  float*          xprojC = (float*)(ws + 26214400L);             // 39,321,600: xproj chunk; att h1/h2 overlay
  unsigned short* h1C    = (unsigned short*)(ws + 26214400L);    //  6,553,600 (overlay on xprojC)
  unsigned short* h2C    = (unsigned short*)(ws + 32768000L);    //  6,553,600 (overlay on xprojC)
  unsigned short* rnn1   = (unsigned short*)(ws + 65536000L);    // 26,214,400
  float*          scores = (float*)(ws + 91750400L);             //    409,600
  float*          alphas = (float*)(ws + 92160000L);             //    409,600
  float*          hstate = (float*)(ws + 92569600L);             //    262,144
  float*          feat   = (float*)(ws + 92831744L);             //  1,048,576
  unsigned short* W1xT   = (unsigned short*)(ws + 93880320L);    //     98,304
  unsigned short* W2xT   = (unsigned short*)(ws + 93978624L);    //     98,304
  unsigned short* AW1T   = (unsigned short*)(ws + 94076928L);    //    131,072
  unsigned short* AW2T   = (unsigned short*)(ws + 94208000L);    //     32,768
  float*          b384_1 = (float*)(ws + 94240768L);             //      1,536
  float*          b384_2 = (float*)(ws + 94242304L);             //      1,536
  float*          bA1    = (float*)(ws + 94243840L);             //        512
  float*          bA2    = (float*)(ws + 94244352L);             //        512

  const size_t chunkRows = (size_t)TC * 512;                     // 25600

  prep_weights<<<256, 256, 0, stream>>>(Wg1, Wc1, Wg2, Wc2, aw1, aw2, bg1, bc1,
                                        bg2, bc2, ab1, ab2,
                                        W1xT, W2xT, AW1T, AW2T, b384_1, b384_2, bA1, bA2);
  cast_his_t<<<12800, 256, 0, stream>>>((const float4*)his, (ushort4*)XhA);
  zero_f<<<256, 256, 0, stream>>>(hstate, 65536);

  // ---- GRU1 over chunks
  for (int c = 0; c < NC; c++) {
    gemm_bt<0><<<dim3(200, 3), 256, 0, stream>>>(XhA + c * chunkRows * 128, W1xT,
                                                 b384_1, xprojC, nullptr, 128, 384);
    gru_chunk<0><<<256, 512, 0, stream>>>(xprojC, Wg1, Wc1, seqlen, nullptr,
                                          rnn1, hstate, c * TC);
  }

  // ---- DIN attention over chunks (XhA reused as din; h1/h2 overlay xprojC)
  for (int c = 0; c < NC; c++) {
    build_din<<<3200, 256, 0, stream>>>(item_eb, rnn1, (ushort4*)XhA, (int)(c * chunkRows));
    gemm_bt<1><<<dim3(200, 1), 256, 0, stream>>>(XhA, AW1T, bA1, nullptr, h1C, 512, 128);
    gemm_bt<1><<<dim3(200, 1), 256, 0, stream>>>(h1C, AW2T, bA2, nullptr, h2C, 128, 128);
    scorer<<<100, 256, 0, stream>>>(h2C, aw3, ab3, scores, c * TC);
  }
  mask_softmax<<<512, 256, 0, stream>>>(scores, seqlen, alphas);

  // ---- AUGRU over chunks
  zero_f<<<256, 256, 0, stream>>>(hstate, 65536);
  for (int c = 0; c < NC; c++) {
    gemm_bt<0><<<dim3(200, 3), 256, 0, stream>>>(rnn1 + c * chunkRows * 128, W2xT,
                                                 b384_2, xprojC, nullptr, 128, 384);
    gru_chunk<1><<<256, 512, 0, stream>>>(xprojC, Wg2, Wc2, seqlen, alphas,
                                          nullptr, hstate, c * TC);
  }

  feat_kernel<<<512, 128, 0, stream>>>(item_eb, his, seqlen, hstate, feat);
  head_kernel<<<512, 256, 0, stream>>>(feat, fc1w, fc1b, al1, fc2w, fc2b, al2,
                                       fc3w, fc3b, (float*)d_out);
}

// Round 3
// 817.531 us; speedup vs baseline: 1.9233x; 1.9233x over previous
//
#include <hip/hip_runtime.h>
#include <hip/hip_bf16.h>

// DIEN (DIN_V2_Gru_Vec_attGru) forward. B=512, T=200, D=128, H=128.
// Chunked pipeline (NC=4 chunks of TC=50 steps), workspace ~94 MB.
// Round 3: gru_chunk rewritten — f16x2-packed h-part weights held in VGPRs
// (v_dot2_f32_f16), 1 row/block x 512 blocks (2 blocks/CU), ping-pong h,
// register prefetch of x preacts, fast tanh.

typedef __attribute__((ext_vector_type(8))) short bf16x8;
typedef __attribute__((ext_vector_type(4))) float f32x4;
typedef _Float16 f16x2 __attribute__((ext_vector_type(2)));

#define NC 4
#define TC 50

static __device__ __forceinline__ unsigned short f2bf(float f) {
  union { __hip_bfloat16 h; unsigned short u; } v;
  v.h = __float2bfloat16(f);
  return v.u;
}
static __device__ __forceinline__ float bf2f(unsigned short u) {
  union { __hip_bfloat16 h; unsigned short u; } v;
  v.u = u;
  return __bfloat162float(v.h);
}
static __device__ __forceinline__ unsigned int pkf16(float a, float b) {
  union { f16x2 v; unsigned int u; } c;
  c.v = (f16x2){(_Float16)a, (_Float16)b};
  return c.u;
}
static __device__ __forceinline__ float dot2f(unsigned int w, unsigned int h, float acc) {
  union { unsigned int u; f16x2 v; } a, b;
  a.u = w; b.u = h;
#if __has_builtin(__builtin_amdgcn_fdot2)
  return __builtin_amdgcn_fdot2(a.v, b.v, acc, false);
#else
  return acc + (float)a.v.x * (float)b.v.x + (float)a.v.y * (float)b.v.y;
#endif
}

// ---------------------------------------------------------------- prep
__global__ __launch_bounds__(256) void prep_weights(
    const float* __restrict__ Wg1, const float* __restrict__ Wc1,
    const float* __restrict__ Wg2, const float* __restrict__ Wc2,
    const float* __restrict__ aw1, const float* __restrict__ aw2,
    const float* __restrict__ bg1, const float* __restrict__ bc1,
    const float* __restrict__ bg2, const float* __restrict__ bc2,
    const float* __restrict__ ab1, const float* __restrict__ ab2,
    unsigned short* __restrict__ W1xT, unsigned short* __restrict__ W2xT,
    unsigned short* __restrict__ AW1T, unsigned short* __restrict__ AW2T,
    float* __restrict__ b384_1, float* __restrict__ b384_2,
    float* __restrict__ bA1, float* __restrict__ bA2,
    unsigned int* __restrict__ WgP1, unsigned int* __restrict__ WcP1,
    unsigned int* __restrict__ WgP2, unsigned int* __restrict__ WcP2)
{
  int e = blockIdx.x * 256 + threadIdx.x;
  if (e < 49152) {              // W1xT/W2xT: [384 n][128 k]; n<256 from Wg, else Wc
    int n = e >> 7, k = e & 127;
    float v1 = (n < 256) ? Wg1[k * 256 + n] : Wc1[k * 128 + (n - 256)];
    float v2 = (n < 256) ? Wg2[k * 256 + n] : Wc2[k * 128 + (n - 256)];
    W1xT[e] = f2bf(v1);
    W2xT[e] = f2bf(v2);
  }
  if (e < 65536) {              // AW1T: [128 n][512 k], pad n>=80 with 0
    int n = e >> 9, k = e & 511;
    AW1T[e] = f2bf(n < 80 ? aw1[k * 80 + n] : 0.f);
  }
  if (e < 16384) {              // AW2T: [128 n][128 k], valid n<40 && k<80
    int n = e >> 7, k = e & 127;
    AW2T[e] = f2bf((n < 40 && k < 80) ? aw2[k * 40 + n] : 0.f);
  }
  if (e < 16384) {              // packed gate h-weights: [32 i][512 t]
    int i = e >> 9, tt = e & 511;
    int jg = tt >> 1, hg = tt & 1;
    int row = 128 + hg * 64 + 2 * i;
    WgP1[e] = pkf16(Wg1[row * 256 + jg], Wg1[(row + 1) * 256 + jg]);
    WgP2[e] = pkf16(Wg2[row * 256 + jg], Wg2[(row + 1) * 256 + jg]);
  }
  if (e < 8192) {               // packed cand h-weights: [16 i][512 t]
    int i = e >> 9, tt = e & 511;
    int jc = tt >> 2, qc = tt & 3;
    int row = 128 + qc * 32 + 2 * i;
    WcP1[e] = pkf16(Wc1[row * 128 + jc], Wc1[(row + 1) * 128 + jc]);
    WcP2[e] = pkf16(Wc2[row * 128 + jc], Wc2[(row + 1) * 128 + jc]);
  }
  if (e < 384) {
    b384_1[e] = (e < 256) ? bg1[e] : bc1[e - 256];
    b384_2[e] = (e < 256) ? bg2[e] : bc2[e - 256];
  }
  if (e < 128) {
    bA1[e] = (e < 80) ? ab1[e] : 0.f;
    bA2[e] = (e < 40) ? ab2[e] : 0.f;
  }
}

__global__ __launch_bounds__(256) void zero_f(float* __restrict__ p, int n) {
  int i = blockIdx.x * 256 + threadIdx.x;
  if (i < n) p[i] = 0.f;
}

// ---------------------------------------------------------------- cast his -> bf16 t-major
__global__ __launch_bounds__(256) void cast_his_t(const float4* __restrict__ in4,
                                                  ushort4* __restrict__ out4)
{
  int i = blockIdx.x * 256 + threadIdx.x;   // 3,276,800 total
  float4 v = in4[i];
  int d4 = (i & 31) << 2;
  int bt = i >> 5;
  int tt = bt % 200, bb = bt / 200;
  out4[(((size_t)tt * 512 + bb) * 128 + d4) >> 2] =
      make_ushort4(f2bf(v.x), f2bf(v.y), f2bf(v.z), f2bf(v.w));
}

// ---------------------------------------------------------------- bf16 MFMA GEMM
template <int EPI>
__global__ __launch_bounds__(256) void gemm_bt(
    const unsigned short* __restrict__ A, const unsigned short* __restrict__ BT,
    const float* __restrict__ bias, float* __restrict__ Cf,
    unsigned short* __restrict__ Cb, int K, int ldc)
{
  __shared__ uint4 AsB[1024];   // 128 rows x 64 bf16, xor-swizzled 16B chunks
  __shared__ uint4 BsB[1024];
  const int tid = threadIdx.x;
  const int w = tid >> 6, l = tid & 63;
  const long mBase = (long)blockIdx.x * 128;
  const int nBase = blockIdx.y * 128;

  f32x4 acc[2][8];
#pragma unroll
  for (int m = 0; m < 2; m++)
#pragma unroll
    for (int n = 0; n < 8; n++) acc[m][n] = 0.f;

  const int srow = (tid >> 3) & 31;
  const int scc = l & 7;

  for (int kb = 0; kb < K; kb += 64) {
#pragma unroll
    for (int p = 0; p < 4; p++) {
      int row = p * 32 + srow;
      uint4 va = *(const uint4*)(A + (size_t)(mBase + row) * K + kb + scc * 8);
      uint4 vb = *(const uint4*)(BT + (size_t)(nBase + row) * K + kb + scc * 8);
      AsB[row * 8 + (scc ^ (row & 7))] = va;
      BsB[row * 8 + (scc ^ (row & 7))] = vb;
    }
    __syncthreads();
#pragma unroll
    for (int ks = 0; ks < 2; ks++) {
      int ccr = ks * 4 + (l >> 4);
      int r0 = w * 32 + (l & 15);
      int r1 = r0 + 16;
      bf16x8 a0 = *(const bf16x8*)&AsB[r0 * 8 + (ccr ^ (r0 & 7))];
      bf16x8 a1 = *(const bf16x8*)&AsB[r1 * 8 + (ccr ^ (r1 & 7))];
#pragma unroll
      for (int n = 0; n < 8; n++) {
        int rb = n * 16 + (l & 15);
        bf16x8 bn = *(const bf16x8*)&BsB[rb * 8 + (ccr ^ (rb & 7))];
        acc[0][n] = __builtin_amdgcn_mfma_f32_16x16x32_bf16(a0, bn, acc[0][n], 0, 0, 0);
        acc[1][n] = __builtin_amdgcn_mfma_f32_16x16x32_bf16(a1, bn, acc[1][n], 0, 0, 0);
      }
    }
    __syncthreads();
  }

  const int lcol = l & 15, lrow4 = (l >> 4) * 4;
#pragma unroll
  for (int n = 0; n < 8; n++) {
    int gcol = nBase + n * 16 + lcol;
    float bb = bias[gcol];
#pragma unroll
    for (int m = 0; m < 2; m++) {
#pragma unroll
      for (int i = 0; i < 4; i++) {
        long grow = mBase + w * 32 + m * 16 + lrow4 + i;
        float v = acc[m][n][i] + bb;
        if (EPI == 0) {
          Cf[grow * ldc + gcol] = v;
        } else {
          Cb[grow * ldc + gcol] = f2bf(1.f / (1.f + __expf(-v)));
        }
      }
    }
  }
}

// ---------------------------------------------------------------- GRU / AUGRU step
// 1 batch row per block, 512 threads.
// gates: thread t -> col jg=t>>1, k-half hg=t&1 (32 packed w)
// cand : thread t -> col jc=t>>2, k-quarter qc=t&3 (16 packed w)
template <int AUGRU>
static __device__ __forceinline__ void gstep(
    int t, int jg, int hg, int jc, int qc, int len, int tg,
    const unsigned int (&wg)[32], const unsigned int (&wc)[16],
    const float (&hFc)[128], const unsigned int (&hHc)[64],
    float (&hFn)[128], unsigned int (&hHn)[64],
    unsigned int (&rghP)[64], float (&uS)[128],
    float& xg, float& xc, float& al,
    const float* __restrict__ xrowN,   // next step's x row (prefetch)
    const float* __restrict__ alphaN,  // next step's alpha addr (AUGRU)
    unsigned short* __restrict__ outp) // this step's bf16 out row (GRU1)
{
  // prefetch next step's x preacts (overlaps with dots below)
  float xg_n = xrowN[jg];
  float xc_n = xrowN[256 + jc];
  float al_n = AUGRU ? *alphaN : 0.f;

  // ---- gates
  float a = 0.f;
#pragma unroll
  for (int q = 0; q < 8; q++) {
    uint4 hq = *(const uint4*)&hHc[hg * 32 + q * 4];
    a = dot2f(wg[q * 4 + 0], hq.x, a);
    a = dot2f(wg[q * 4 + 1], hq.y, a);
    a = dot2f(wg[q * 4 + 2], hq.z, a);
    a = dot2f(wg[q * 4 + 3], hq.w, a);
  }
  a += __shfl_xor(a, 1);
  a += xg;
  float g = 1.f / (1.f + __expf(-a));
  if (jg < 128) {                    // wave-uniform branch
    float rgh = g * hFc[jg];
    float rghHi = __shfl_down(rgh, 2);
    if ((t & 3) == 0) rghP[jg >> 1] = pkf16(rgh, rghHi);
  } else {
    if (hg == 0) uS[jg - 128] = g;
  }
  __syncthreads();

  // ---- candidate + state update
  float c = 0.f;
#pragma unroll
  for (int q = 0; q < 4; q++) {
    uint4 rq = *(const uint4*)&rghP[qc * 16 + q * 4];
    c = dot2f(wc[q * 4 + 0], rq.x, c);
    c = dot2f(wc[q * 4 + 1], rq.y, c);
    c = dot2f(wc[q * 4 + 2], rq.z, c);
    c = dot2f(wc[q * 4 + 3], rq.w, c);
  }
  c += __shfl_xor(c, 1);
  c += __shfl_xor(c, 2);
  c += xc;
  c = fminf(fmaxf(c, -15.f), 15.f);
  float e2 = __expf(2.f * c);
  c = 1.f - 2.f / (e2 + 1.f);        // tanh
  float u = uS[jc];
  if (AUGRU) u *= (1.f - al);
  float hc = hFc[jc];
  float hn = u * hc + (1.f - u) * c;
  bool valid = tg < len;
  hn = valid ? hn : hc;
  float hnHi = __shfl_down(hn, 4);
  if (qc == 0) {
    hFn[jc] = hn;
    if (!AUGRU) outp[jc] = f2bf(valid ? hn : 0.f);
  }
  if ((t & 7) == 0) hHn[jc >> 1] = pkf16(hn, hnHi);
  __syncthreads();

  xg = xg_n; xc = xc_n; al = al_n;
}

template <int AUGRU>
__global__ __launch_bounds__(512, 4) void gru_chunk(
    const float* __restrict__ xproj,       // [TC][512][384] t-major chunk
    const unsigned int* __restrict__ WgP,  // [32][512] packed f16 pairs
    const unsigned int* __restrict__ WcP,  // [16][512]
    const int* __restrict__ seqlen,
    const float* __restrict__ alphas,      // [B][200] (AUGRU only)
    unsigned short* __restrict__ outbf,    // [T][B][128] bf16 (GRU1 only)
    float* __restrict__ hstate,            // [B][128] f32 in/out
    int tbase)
{
  const int t = threadIdx.x;
  const int r = blockIdx.x;
  const int jg = t >> 1, hg = t & 1;
  const int jc = t >> 2, qc = t & 3;

  unsigned int wg[32], wc[16];
#pragma unroll
  for (int i = 0; i < 32; i++) wg[i] = WgP[i * 512 + t];
#pragma unroll
  for (int i = 0; i < 16; i++) wc[i] = WcP[i * 512 + t];

  __shared__ float hF[2][128];
  __shared__ unsigned int hH[2][64];
  __shared__ unsigned int rghP[64];
  __shared__ float uS[128];

  if (t < 128) hF[0][t] = hstate[r * 128 + t];
  if (t < 64) hH[0][t] = pkf16(hstate[r * 128 + 2 * t], hstate[r * 128 + 2 * t + 1]);
  const int len = seqlen[r];
  __syncthreads();

  const size_t rowStride = 512 * 384;
  const float* xr0 = xproj + (size_t)r * 384;
  float xg = xr0[jg];
  float xc = xr0[256 + jc];
  float al = AUGRU ? alphas[r * 200 + tbase] : 0.f;

  for (int ts = 0; ts < TC; ts += 2) {
    {
      int tsn = (ts + 1 < TC) ? ts + 1 : TC - 1;
      const float* xrn = xproj + (size_t)tsn * rowStride + (size_t)r * 384;
      const float* aln = alphas + (AUGRU ? (size_t)r * 200 + min(tbase + ts + 1, 199) : 0);
      unsigned short* outp = outbf + ((size_t)(tbase + ts) * 512 + r) * 128;
      gstep<AUGRU>(t, jg, hg, jc, qc, len, tbase + ts, wg, wc,
                   hF[0], hH[0], hF[1], hH[1], rghP, uS,
                   xg, xc, al, xrn, aln, outp);
    }
    {
      int tsn = (ts + 2 < TC) ? ts + 2 : TC - 1;
      const float* xrn = xproj + (size_t)tsn * rowStride + (size_t)r * 384;
      const float* aln = alphas + (AUGRU ? (size_t)r * 200 + min(tbase + ts + 2, 199) : 0);
      unsigned short* outp = outbf + ((size_t)(tbase + ts + 1) * 512 + r) * 128;
      gstep<AUGRU>(t, jg, hg, jc, qc, len, tbase + ts + 1, wg, wc,
                   hF[1], hH[1], hF[0], hH[0], rghP, uS,
                   xg, xc, al, xrn, aln, outp);
    }
  }
  if (t < 128) hstate[r * 128 + t] = hF[0][t];
}

// ---------------------------------------------------------------- din build (per chunk)
__global__ __launch_bounds__(256) void build_din(
    const float* __restrict__ item_eb, const unsigned short* __restrict__ rnn1bf,
    ushort4* __restrict__ din, int rowbase)
{
  int i = blockIdx.x * 256 + threadIdx.x;   // TC*512*32 threads, 4 cols each
  int r = i >> 5;                           // row within chunk (t-major: t'*512+b)
  int d4 = (i & 31) << 2;
  int b = r & 511;
  float4 q = *(const float4*)(item_eb + b * 128 + d4);
  const unsigned short* rp = rnn1bf + ((size_t)rowbase + r) * 128 + d4;
  unsigned short s0 = rp[0], s1 = rp[1], s2 = rp[2], s3 = rp[3];
  float r0 = bf2f(s0), r1 = bf2f(s1), r2 = bf2f(s2), r3 = bf2f(s3);
  size_t base = (size_t)r * 512 + d4;
  din[(base + 0) >> 2]   = make_ushort4(f2bf(q.x), f2bf(q.y), f2bf(q.z), f2bf(q.w));
  din[(base + 128) >> 2] = make_ushort4(s0, s1, s2, s3);
  din[(base + 256) >> 2] = make_ushort4(f2bf(q.x - r0), f2bf(q.y - r1), f2bf(q.z - r2), f2bf(q.w - r3));
  din[(base + 384) >> 2] = make_ushort4(f2bf(q.x * r0), f2bf(q.y * r1), f2bf(q.z * r2), f2bf(q.w * r3));
}

// ---------------------------------------------------------------- scorer (per chunk)
__global__ __launch_bounds__(256) void scorer(
    const unsigned short* __restrict__ h2, const float* __restrict__ w3,
    const float* __restrict__ b3, float* __restrict__ scores, int tbase)
{
  int r = blockIdx.x * 256 + threadIdx.x;   // [0, TC*512)
  int b = r & 511, tp = r >> 9;
  const unsigned short* row = h2 + (size_t)r * 128;
  float acc = b3[0];
#pragma unroll 8
  for (int k = 0; k < 40; k++) acc += bf2f(row[k]) * w3[k];
  scores[b * 200 + tbase + tp] = acc;
}

// ---------------------------------------------------------------- masked softmax
__global__ __launch_bounds__(256) void mask_softmax(
    const float* __restrict__ scores, const int* __restrict__ seqlen,
    float* __restrict__ alphas)
{
  int b = blockIdx.x, t = threadIdx.x;
  __shared__ float red[256];
  int len = seqlen[b];
  float s = (t < 200 && t < len) ? scores[b * 200 + t] : -1e30f;
  red[t] = s;
  __syncthreads();
  for (int o = 128; o > 0; o >>= 1) {
    if (t < o) red[t] = fmaxf(red[t], red[t + o]);
    __syncthreads();
  }
  float m = red[0];
  __syncthreads();
  float e = (t < 200 && t < len) ? __expf(s - m) : 0.f;
  red[t] = e;
  __syncthreads();
  for (int o = 128; o > 0; o >>= 1) {
    if (t < o) red[t] += red[t + o];
    __syncthreads();
  }
  float denom = red[0];
  if (t < 200) alphas[b * 200 + t] = e / denom;
}

// ---------------------------------------------------------------- his_sum + feat (f32)
__global__ __launch_bounds__(128) void feat_kernel(
    const float* __restrict__ item_eb, const float* __restrict__ his,
    const int* __restrict__ seqlen, const float* __restrict__ hT,
    float* __restrict__ feat)
{
  int b = blockIdx.x, d = threadIdx.x;
  int len = seqlen[b];
  float s = 0.f;
  const float* hp = his + (size_t)b * 200 * 128 + d;
  for (int ts = 0; ts < len; ++ts) s += hp[ts * 128];
  float q = item_eb[b * 128 + d];
  feat[b * 512 + d] = q;
  feat[b * 512 + 128 + d] = s;
  feat[b * 512 + 256 + d] = q * s;
  feat[b * 512 + 384 + d] = hT[b * 128 + d];
}

// ---------------------------------------------------------------- f32 head
__global__ __launch_bounds__(256) void head_kernel(
    const float* __restrict__ feat,
    const float* __restrict__ w1, const float* __restrict__ b1, const float* __restrict__ a1,
    const float* __restrict__ w2, const float* __restrict__ b2, const float* __restrict__ a2,
    const float* __restrict__ w3, const float* __restrict__ b3,
    float* __restrict__ out)
{
  int b = blockIdx.x, t = threadIdx.x;
  __shared__ float frow[512];
  __shared__ float z1[200];
  __shared__ float z2[80];
  frow[t] = feat[b * 512 + t];
  frow[256 + t] = feat[b * 512 + 256 + t];
  __syncthreads();
  if (t < 200) {
    float acc = b1[t];
#pragma unroll 8
    for (int k = 0; k < 512; k++) acc += frow[k] * w1[k * 200 + t];
    z1[t] = acc > 0.f ? acc : a1[t] * acc;
  }
  __syncthreads();
  if (t < 80) {
    float acc = b2[t];
#pragma unroll 8
    for (int k = 0; k < 200; k++) acc += z1[k] * w2[k * 80 + t];
    z2[t] = acc > 0.f ? acc : a2[t] * acc;
  }
  __syncthreads();
  if (t == 0) {
    float l0 = b3[0], l1 = b3[1];
    for (int k = 0; k < 80; k++) {
      float z = z2[k];
      l0 += z * w3[k * 2];
      l1 += z * w3[k * 2 + 1];
    }
    float m = fmaxf(l0, l1);
    float e0 = __expf(l0 - m), e1 = __expf(l1 - m);
    out[b * 2 + 0] = e0 / (e0 + e1);
    out[b * 2 + 1] = e1 / (e0 + e1);
  }
}

// ---------------------------------------------------------------- launch
extern "C" void kernel_launch(void* const* d_in, const int* in_sizes, int n_in,
                              void* d_out, int out_size, void* d_ws, size_t ws_size,
                              hipStream_t stream)
{
  const float* item_eb = (const float*)d_in[0];
  const float* his     = (const float*)d_in[1];
  const float* Wg1     = (const float*)d_in[2];
  const float* bg1     = (const float*)d_in[3];
  const float* Wc1     = (const float*)d_in[4];
  const float* bc1     = (const float*)d_in[5];
  const float* aw1     = (const float*)d_in[6];
  const float* ab1     = (const float*)d_in[7];
  const float* aw2     = (const float*)d_in[8];
  const float* ab2     = (const float*)d_in[9];
  const float* aw3     = (const float*)d_in[10];
  const float* ab3     = (const float*)d_in[11];
  const float* Wg2     = (const float*)d_in[12];
  const float* bg2     = (const float*)d_in[13];
  const float* Wc2     = (const float*)d_in[14];
  const float* bc2     = (const float*)d_in[15];
  const float* fc1w    = (const float*)d_in[16];
  const float* fc1b    = (const float*)d_in[17];
  const float* al1     = (const float*)d_in[18];
  const float* fc2w    = (const float*)d_in[19];
  const float* fc2b    = (const float*)d_in[20];
  const float* al2     = (const float*)d_in[21];
  const float* fc3w    = (const float*)d_in[22];
  const float* fc3b    = (const float*)d_in[23];
  const int*   seqlen  = (const int*)d_in[24];

  // ---- workspace layout (~94.3 MB peak, regions reused across phases)
  char* ws = (char*)d_ws;
  unsigned short* XhA    = (unsigned short*)(ws + 0L);           // 26,214,400: Xh_t, later din chunk
  float*          xprojC = (float*)(ws + 26214400L);             // 39,321,600: xproj chunk; att h1/h2 overlay
  unsigned short* h1C    = (unsigned short*)(ws + 26214400L);    //  6,553,600 (overlay on xprojC)
  unsigned short* h2C    = (unsigned short*)(ws + 32768000L);    //  6,553,600 (overlay on xprojC)
  unsigned short* rnn1   = (unsigned short*)(ws + 65536000L);    // 26,214,400
  float*          scores = (float*)(ws + 91750400L);             //    409,600
  float*          alphas = (float*)(ws + 92160000L);             //    409,600
  float*          hstate = (float*)(ws + 92569600L);             //    262,144
  float*          feat   = (float*)(ws + 92831744L);             //  1,048,576
  // packed GRU h-weights overlay the (later-written) feat region:
  unsigned int*   WgP1   = (unsigned int*)(ws + 92831744L);      //     65,536
  unsigned int*   WcP1   = (unsigned int*)(ws + 92897280L);      //     32,768
  unsigned int*   WgP2   = (unsigned int*)(ws + 92930048L);      //     65,536
  unsigned int*   WcP2   = (unsigned int*)(ws + 92995584L);      //     32,768
  unsigned short* W1xT   = (unsigned short*)(ws + 93880320L);    //     98,304
  unsigned short* W2xT   = (unsigned short*)(ws + 93978624L);    //     98,304
  unsigned short* AW1T   = (unsigned short*)(ws + 94076928L);    //    131,072
  unsigned short* AW2T   = (unsigned short*)(ws + 94208000L);    //     32,768
  float*          b384_1 = (float*)(ws + 94240768L);             //      1,536
  float*          b384_2 = (float*)(ws + 94242304L);             //      1,536
  float*          bA1    = (float*)(ws + 94243840L);             //        512
  float*          bA2    = (float*)(ws + 94244352L);             //        512

  const size_t chunkRows = (size_t)TC * 512;                     // 25600

  prep_weights<<<256, 256, 0, stream>>>(Wg1, Wc1, Wg2, Wc2, aw1, aw2, bg1, bc1,
                                        bg2, bc2, ab1, ab2,
                                        W1xT, W2xT, AW1T, AW2T, b384_1, b384_2, bA1, bA2,
                                        WgP1, WcP1, WgP2, WcP2);
  cast_his_t<<<12800, 256, 0, stream>>>((const float4*)his, (ushort4*)XhA);
  zero_f<<<256, 256, 0, stream>>>(hstate, 65536);

  // ---- GRU1 over chunks
  for (int c = 0; c < NC; c++) {
    gemm_bt<0><<<dim3(200, 3), 256, 0, stream>>>(XhA + c * chunkRows * 128, W1xT,
                                                 b384_1, xprojC, nullptr, 128, 384);
    gru_chunk<0><<<512, 512, 0, stream>>>(xprojC, WgP1, WcP1, seqlen, nullptr,
                                          rnn1, hstate, c * TC);
  }

  // ---- DIN attention over chunks (XhA reused as din; h1/h2 overlay xprojC)
  for (int c = 0; c < NC; c++) {
    build_din<<<3200, 256, 0, stream>>>(item_eb, rnn1, (ushort4*)XhA, (int)(c * chunkRows));
    gemm_bt<1><<<dim3(200, 1), 256, 0, stream>>>(XhA, AW1T, bA1, nullptr, h1C, 512, 128);
    gemm_bt<1><<<dim3(200, 1), 256, 0, stream>>>(h1C, AW2T, bA2, nullptr, h2C, 128, 128);
    scorer<<<100, 256, 0, stream>>>(h2C, aw3, ab3, scores, c * TC);
  }
  mask_softmax<<<512, 256, 0, stream>>>(scores, seqlen, alphas);

  // ---- AUGRU over chunks
  zero_f<<<256, 256, 0, stream>>>(hstate, 65536);
  for (int c = 0; c < NC; c++) {
    gemm_bt<0><<<dim3(200, 3), 256, 0, stream>>>(rnn1 + c * chunkRows * 128, W2xT,
                                                 b384_2, xprojC, nullptr, 128, 384);
    gru_chunk<1><<<512, 512, 0, stream>>>(xprojC, WgP2, WcP2, seqlen, alphas,
                                          nullptr, hstate, c * TC);
  }

  feat_kernel<<<512, 128, 0, stream>>>(item_eb, his, seqlen, hstate, feat);
  head_kernel<<<512, 256, 0, stream>>>(feat, fc1w, fc1b, al1, fc2w, fc2b, al2,
                                       fc3w, fc3b, (float*)d_out);
}

// Round 4
// 744.188 us; speedup vs baseline: 2.1129x; 1.0986x over previous
//
#include <hip/hip_runtime.h>
#include <hip/hip_bf16.h>

// DIEN (DIN_V2_Gru_Vec_attGru) forward. B=512, T=200, D=128, H=128.
// Round 4: gru_chunk -> 256 thr/row (1 gate col/thread, no gate reduce),
// early-exit on seq_len, f16 xproj (halved traffic), split accumulators.

typedef __attribute__((ext_vector_type(8))) short bf16x8;
typedef __attribute__((ext_vector_type(4))) float f32x4;
typedef _Float16 f16x2 __attribute__((ext_vector_type(2)));

#define NC 4
#define TC 50

static __device__ __forceinline__ unsigned short f2bf(float f) {
  union { __hip_bfloat16 h; unsigned short u; } v;
  v.h = __float2bfloat16(f);
  return v.u;
}
static __device__ __forceinline__ float bf2f(unsigned short u) {
  union { __hip_bfloat16 h; unsigned short u; } v;
  v.u = u;
  return __bfloat162float(v.h);
}
static __device__ __forceinline__ unsigned short f2h(float f) {
  union { _Float16 h; unsigned short u; } v;
  v.h = (_Float16)f;
  return v.u;
}
static __device__ __forceinline__ unsigned int pkf16(float a, float b) {
  union { f16x2 v; unsigned int u; } c;
  c.v = (f16x2){(_Float16)a, (_Float16)b};
  return c.u;
}
static __device__ __forceinline__ float dot2f(unsigned int w, unsigned int h, float acc) {
  union { unsigned int u; f16x2 v; } a, b;
  a.u = w; b.u = h;
#if __has_builtin(__builtin_amdgcn_fdot2)
  return __builtin_amdgcn_fdot2(a.v, b.v, acc, false);
#else
  return acc + (float)a.v.x * (float)b.v.x + (float)a.v.y * (float)b.v.y;
#endif
}

// ---------------------------------------------------------------- prep
__global__ __launch_bounds__(256) void prep_weights(
    const float* __restrict__ Wg1, const float* __restrict__ Wc1,
    const float* __restrict__ Wg2, const float* __restrict__ Wc2,
    const float* __restrict__ aw1, const float* __restrict__ aw2,
    const float* __restrict__ bg1, const float* __restrict__ bc1,
    const float* __restrict__ bg2, const float* __restrict__ bc2,
    const float* __restrict__ ab1, const float* __restrict__ ab2,
    unsigned short* __restrict__ W1xT, unsigned short* __restrict__ W2xT,
    unsigned short* __restrict__ AW1T, unsigned short* __restrict__ AW2T,
    float* __restrict__ b384_1, float* __restrict__ b384_2,
    float* __restrict__ bA1, float* __restrict__ bA2,
    unsigned int* __restrict__ WgP1, unsigned int* __restrict__ WcP1,
    unsigned int* __restrict__ WgP2, unsigned int* __restrict__ WcP2)
{
  int e = blockIdx.x * 256 + threadIdx.x;
  if (e < 49152) {              // W1xT/W2xT: [384 n][128 k]; n<256 from Wg, else Wc
    int n = e >> 7, k = e & 127;
    float v1 = (n < 256) ? Wg1[k * 256 + n] : Wc1[k * 128 + (n - 256)];
    float v2 = (n < 256) ? Wg2[k * 256 + n] : Wc2[k * 128 + (n - 256)];
    W1xT[e] = f2bf(v1);
    W2xT[e] = f2bf(v2);
  }
  if (e < 65536) {              // AW1T: [128 n][512 k], pad n>=80 with 0
    int n = e >> 9, k = e & 511;
    AW1T[e] = f2bf(n < 80 ? aw1[k * 80 + n] : 0.f);
  }
  if (e < 16384) {              // AW2T: [128 n][128 k], valid n<40 && k<80
    int n = e >> 7, k = e & 127;
    AW2T[e] = f2bf((n < 40 && k < 80) ? aw2[k * 40 + n] : 0.f);
  }
  if (e < 16384) {              // WgP: [64 i][256 t]; thread t owns gate col t
    int i = e >> 8, tt = e & 255;
    int row = 128 + 2 * i;
    WgP1[e] = pkf16(Wg1[row * 256 + tt], Wg1[(row + 1) * 256 + tt]);
    WgP2[e] = pkf16(Wg2[row * 256 + tt], Wg2[(row + 1) * 256 + tt]);
  }
  if (e < 8192) {               // WcP: [32 i][256 t]; thread t: col t>>1, k-half t&1
    int i = e >> 8, tt = e & 255;
    int jc = tt >> 1, half = tt & 1;
    int row = 128 + half * 64 + 2 * i;
    WcP1[e] = pkf16(Wc1[row * 128 + jc], Wc1[(row + 1) * 128 + jc]);
    WcP2[e] = pkf16(Wc2[row * 128 + jc], Wc2[(row + 1) * 128 + jc]);
  }
  if (e < 384) {
    b384_1[e] = (e < 256) ? bg1[e] : bc1[e - 256];
    b384_2[e] = (e < 256) ? bg2[e] : bc2[e - 256];
  }
  if (e < 128) {
    bA1[e] = (e < 80) ? ab1[e] : 0.f;
    bA2[e] = (e < 40) ? ab2[e] : 0.f;
  }
}

__global__ __launch_bounds__(256) void zero_f(float* __restrict__ p, int n) {
  int i = blockIdx.x * 256 + threadIdx.x;
  if (i < n) p[i] = 0.f;
}

// ---------------------------------------------------------------- cast his -> bf16 t-major
__global__ __launch_bounds__(256) void cast_his_t(const float4* __restrict__ in4,
                                                  ushort4* __restrict__ out4)
{
  int i = blockIdx.x * 256 + threadIdx.x;   // 3,276,800 total
  float4 v = in4[i];
  int d4 = (i & 31) << 2;
  int bt = i >> 5;
  int tt = bt % 200, bb = bt / 200;
  out4[(((size_t)tt * 512 + bb) * 128 + d4) >> 2] =
      make_ushort4(f2bf(v.x), f2bf(v.y), f2bf(v.z), f2bf(v.w));
}

// ---------------------------------------------------------------- bf16 MFMA GEMM
// EPI 0: f32 out. EPI 1: bf16 out + sigmoid. EPI 2: f16 out.
template <int EPI>
__global__ __launch_bounds__(256) void gemm_bt(
    const unsigned short* __restrict__ A, const unsigned short* __restrict__ BT,
    const float* __restrict__ bias, float* __restrict__ Cf,
    unsigned short* __restrict__ Cb, int K, int ldc)
{
  __shared__ uint4 AsB[1024];   // 128 rows x 64 bf16, xor-swizzled 16B chunks
  __shared__ uint4 BsB[1024];
  const int tid = threadIdx.x;
  const int w = tid >> 6, l = tid & 63;
  const long mBase = (long)blockIdx.x * 128;
  const int nBase = blockIdx.y * 128;

  f32x4 acc[2][8];
#pragma unroll
  for (int m = 0; m < 2; m++)
#pragma unroll
    for (int n = 0; n < 8; n++) acc[m][n] = 0.f;

  const int srow = (tid >> 3) & 31;
  const int scc = l & 7;

  for (int kb = 0; kb < K; kb += 64) {
#pragma unroll
    for (int p = 0; p < 4; p++) {
      int row = p * 32 + srow;
      uint4 va = *(const uint4*)(A + (size_t)(mBase + row) * K + kb + scc * 8);
      uint4 vb = *(const uint4*)(BT + (size_t)(nBase + row) * K + kb + scc * 8);
      AsB[row * 8 + (scc ^ (row & 7))] = va;
      BsB[row * 8 + (scc ^ (row & 7))] = vb;
    }
    __syncthreads();
#pragma unroll
    for (int ks = 0; ks < 2; ks++) {
      int ccr = ks * 4 + (l >> 4);
      int r0 = w * 32 + (l & 15);
      int r1 = r0 + 16;
      bf16x8 a0 = *(const bf16x8*)&AsB[r0 * 8 + (ccr ^ (r0 & 7))];
      bf16x8 a1 = *(const bf16x8*)&AsB[r1 * 8 + (ccr ^ (r1 & 7))];
#pragma unroll
      for (int n = 0; n < 8; n++) {
        int rb = n * 16 + (l & 15);
        bf16x8 bn = *(const bf16x8*)&BsB[rb * 8 + (ccr ^ (rb & 7))];
        acc[0][n] = __builtin_amdgcn_mfma_f32_16x16x32_bf16(a0, bn, acc[0][n], 0, 0, 0);
        acc[1][n] = __builtin_amdgcn_mfma_f32_16x16x32_bf16(a1, bn, acc[1][n], 0, 0, 0);
      }
    }
    __syncthreads();
  }

  const int lcol = l & 15, lrow4 = (l >> 4) * 4;
#pragma unroll
  for (int n = 0; n < 8; n++) {
    int gcol = nBase + n * 16 + lcol;
    float bb = bias[gcol];
#pragma unroll
    for (int m = 0; m < 2; m++) {
#pragma unroll
      for (int i = 0; i < 4; i++) {
        long grow = mBase + w * 32 + m * 16 + lrow4 + i;
        float v = acc[m][n][i] + bb;
        if (EPI == 0) {
          Cf[grow * ldc + gcol] = v;
        } else if (EPI == 1) {
          Cb[grow * ldc + gcol] = f2bf(1.f / (1.f + __expf(-v)));
        } else {
          Cb[grow * ldc + gcol] = f2h(v);
        }
      }
    }
  }
}

// ---------------------------------------------------------------- GRU / AUGRU chunk
// 1 row/block, 256 threads. Gates: thread t -> col t (wg[64] packed words).
// Cand: thread t -> col t>>1, k-half t&1 (wc[32]). Early-exit past seq_len.
template <int AUGRU>
__global__ __launch_bounds__(256, 3) void gru_chunk(
    const unsigned short* __restrict__ xproj,  // f16 [TC][512][384] t-major
    const unsigned int* __restrict__ WgP,      // [64][256]
    const unsigned int* __restrict__ WcP,      // [32][256]
    const int* __restrict__ seqlen,
    const float* __restrict__ alphas,          // [B][200] (AUGRU only)
    unsigned short* __restrict__ outbf,        // [T][B][128] bf16 (GRU1 only)
    float* __restrict__ hstate,                // [B][128] f32 in/out
    int tbase)
{
  const int t = threadIdx.x;
  const int r = blockIdx.x;
  const int jc = t >> 1, half = t & 1;
  const int len = seqlen[r];
  int nsteps = len - tbase;
  if (nsteps > TC) nsteps = TC;

  if (nsteps <= 0) {
    if (!AUGRU) {
      for (int s = 0; s < TC; s++) {
        unsigned int* zp = (unsigned int*)(outbf + ((size_t)(tbase + s) * 512 + r) * 128);
        if (t < 64) zp[t] = 0;
      }
    }
    return;
  }

  unsigned int wg[64], wc[32];
#pragma unroll
  for (int i = 0; i < 64; i++) wg[i] = WgP[i * 256 + t];
#pragma unroll
  for (int i = 0; i < 32; i++) wc[i] = WcP[i * 256 + t];

  __shared__ float hF[128];
  __shared__ float uF[128];
  __shared__ unsigned int hH[64];
  __shared__ unsigned int rghP[64];

  if (t < 128) hF[t] = hstate[r * 128 + t];
  if (t < 64) hH[t] = pkf16(hstate[r * 128 + 2 * t], hstate[r * 128 + 2 * t + 1]);
  __syncthreads();

  const _Float16* xp = (const _Float16*)xproj;
  const size_t rowStride = (size_t)512 * 384;
  float xg = (float)xp[(size_t)r * 384 + t];
  float xc = (float)xp[(size_t)r * 384 + 256 + jc];
  float al = AUGRU ? alphas[r * 200 + tbase] : 0.f;

  for (int ts = 0; ts < nsteps; ++ts) {
    // ---- gates (full col per thread, 4-way split accumulators)
    float a0 = 0.f, a1 = 0.f, a2 = 0.f, a3 = 0.f;
#pragma unroll
    for (int q = 0; q < 4; q++) {
      uint4 h0 = *(const uint4*)&hH[q * 16 + 0];
      uint4 h1 = *(const uint4*)&hH[q * 16 + 4];
      uint4 h2 = *(const uint4*)&hH[q * 16 + 8];
      uint4 h3 = *(const uint4*)&hH[q * 16 + 12];
      a0 = dot2f(wg[q * 16 + 0], h0.x, a0);  a1 = dot2f(wg[q * 16 + 1], h0.y, a1);
      a2 = dot2f(wg[q * 16 + 2], h0.z, a2);  a3 = dot2f(wg[q * 16 + 3], h0.w, a3);
      a0 = dot2f(wg[q * 16 + 4], h1.x, a0);  a1 = dot2f(wg[q * 16 + 5], h1.y, a1);
      a2 = dot2f(wg[q * 16 + 6], h1.z, a2);  a3 = dot2f(wg[q * 16 + 7], h1.w, a3);
      a0 = dot2f(wg[q * 16 + 8], h2.x, a0);  a1 = dot2f(wg[q * 16 + 9], h2.y, a1);
      a2 = dot2f(wg[q * 16 + 10], h2.z, a2); a3 = dot2f(wg[q * 16 + 11], h2.w, a3);
      a0 = dot2f(wg[q * 16 + 12], h3.x, a0); a1 = dot2f(wg[q * 16 + 13], h3.y, a1);
      a2 = dot2f(wg[q * 16 + 14], h3.z, a2); a3 = dot2f(wg[q * 16 + 15], h3.w, a3);
    }
    float a = (a0 + a1) + (a2 + a3) + xg;
    float g = 1.f / (1.f + __expf(-a));
    float rgh = 0.f;
    if (t < 128) rgh = g * hF[t];
    float rh2 = __shfl_down(rgh, 1);
    if (t < 128) {
      if ((t & 1) == 0) rghP[t >> 1] = pkf16(rgh, rh2);
    } else {
      uF[t - 128] = g;
    }
    // prefetch next step's x preacts / alpha
    int tsn = (ts + 1 < nsteps) ? ts + 1 : nsteps - 1;
    float xg_n = (float)xp[(size_t)tsn * rowStride + (size_t)r * 384 + t];
    float xc_n = (float)xp[(size_t)tsn * rowStride + (size_t)r * 384 + 256 + jc];
    float al_n = AUGRU ? alphas[r * 200 + tbase + tsn] : 0.f;
    __syncthreads();

    // ---- candidate (half col per thread) + state update
    float c0 = 0.f, c1 = 0.f;
    const uint4* rp = (const uint4*)&rghP[half * 32];
#pragma unroll
    for (int q = 0; q < 8; q++) {
      uint4 rq = rp[q];
      c0 = dot2f(wc[q * 4 + 0], rq.x, c0);
      c1 = dot2f(wc[q * 4 + 1], rq.y, c1);
      c0 = dot2f(wc[q * 4 + 2], rq.z, c0);
      c1 = dot2f(wc[q * 4 + 3], rq.w, c1);
    }
    float c = c0 + c1;
    c += __shfl_xor(c, 1);
    c += xc;
    c = fminf(fmaxf(c, -15.f), 15.f);
    float e2 = __expf(2.f * c);
    c = 1.f - 2.f / (e2 + 1.f);        // tanh
    float u = uF[jc];
    if (AUGRU) u *= (1.f - al);
    float h = hF[jc];
    float hn = u * h + (1.f - u) * c;
    float hnHi = __shfl_down(hn, 2);
    if ((t & 1) == 0) {
      hF[jc] = hn;
      if (!AUGRU) outbf[((size_t)(tbase + ts) * 512 + r) * 128 + jc] = f2bf(hn);
    }
    if ((t & 3) == 0) hH[t >> 2] = pkf16(hn, hnHi);
    __syncthreads();

    xg = xg_n; xc = xc_n; al = al_n;
  }

  if (t < 128) hstate[r * 128 + t] = hF[t];
  if (!AUGRU && nsteps < TC) {       // zero-fill masked steps
    for (int s = nsteps; s < TC; s++) {
      unsigned int* zp = (unsigned int*)(outbf + ((size_t)(tbase + s) * 512 + r) * 128);
      if (t < 64) zp[t] = 0;
    }
  }
}

// ---------------------------------------------------------------- din build (per chunk)
__global__ __launch_bounds__(256) void build_din(
    const float* __restrict__ item_eb, const unsigned short* __restrict__ rnn1bf,
    ushort4* __restrict__ din, int rowbase)
{
  int i = blockIdx.x * 256 + threadIdx.x;   // TC*512*32 threads, 4 cols each
  int r = i >> 5;                           // row within chunk (t-major: t'*512+b)
  int d4 = (i & 31) << 2;
  int b = r & 511;
  float4 q = *(const float4*)(item_eb + b * 128 + d4);
  const unsigned short* rp = rnn1bf + ((size_t)rowbase + r) * 128 + d4;
  unsigned short s0 = rp[0], s1 = rp[1], s2 = rp[2], s3 = rp[3];
  float r0 = bf2f(s0), r1 = bf2f(s1), r2 = bf2f(s2), r3 = bf2f(s3);
  size_t base = (size_t)r * 512 + d4;
  din[(base + 0) >> 2]   = make_ushort4(f2bf(q.x), f2bf(q.y), f2bf(q.z), f2bf(q.w));
  din[(base + 128) >> 2] = make_ushort4(s0, s1, s2, s3);
  din[(base + 256) >> 2] = make_ushort4(f2bf(q.x - r0), f2bf(q.y - r1), f2bf(q.z - r2), f2bf(q.w - r3));
  din[(base + 384) >> 2] = make_ushort4(f2bf(q.x * r0), f2bf(q.y * r1), f2bf(q.z * r2), f2bf(q.w * r3));
}

// ---------------------------------------------------------------- scorer (per chunk)
__global__ __launch_bounds__(256) void scorer(
    const unsigned short* __restrict__ h2, const float* __restrict__ w3,
    const float* __restrict__ b3, float* __restrict__ scores, int tbase)
{
  int r = blockIdx.x * 256 + threadIdx.x;   // [0, TC*512)
  int b = r & 511, tp = r >> 9;
  const unsigned short* row = h2 + (size_t)r * 128;
  float acc = b3[0];
#pragma unroll 8
  for (int k = 0; k < 40; k++) acc += bf2f(row[k]) * w3[k];
  scores[b * 200 + tbase + tp] = acc;
}

// ---------------------------------------------------------------- masked softmax
__global__ __launch_bounds__(256) void mask_softmax(
    const float* __restrict__ scores, const int* __restrict__ seqlen,
    float* __restrict__ alphas)
{
  int b = blockIdx.x, t = threadIdx.x;
  __shared__ float red[256];
  int len = seqlen[b];
  float s = (t < 200 && t < len) ? scores[b * 200 + t] : -1e30f;
  red[t] = s;
  __syncthreads();
  for (int o = 128; o > 0; o >>= 1) {
    if (t < o) red[t] = fmaxf(red[t], red[t + o]);
    __syncthreads();
  }
  float m = red[0];
  __syncthreads();
  float e = (t < 200 && t < len) ? __expf(s - m) : 0.f;
  red[t] = e;
  __syncthreads();
  for (int o = 128; o > 0; o >>= 1) {
    if (t < o) red[t] += red[t + o];
    __syncthreads();
  }
  float denom = red[0];
  if (t < 200) alphas[b * 200 + t] = e / denom;
}

// ---------------------------------------------------------------- his_sum + feat (f32)
__global__ __launch_bounds__(128) void feat_kernel(
    const float* __restrict__ item_eb, const float* __restrict__ his,
    const int* __restrict__ seqlen, const float* __restrict__ hT,
    float* __restrict__ feat)
{
  int b = blockIdx.x, d = threadIdx.x;
  int len = seqlen[b];
  float s = 0.f;
  const float* hp = his + (size_t)b * 200 * 128 + d;
  for (int ts = 0; ts < len; ++ts) s += hp[ts * 128];
  float q = item_eb[b * 128 + d];
  feat[b * 512 + d] = q;
  feat[b * 512 + 128 + d] = s;
  feat[b * 512 + 256 + d] = q * s;
  feat[b * 512 + 384 + d] = hT[b * 128 + d];
}

// ---------------------------------------------------------------- f32 head
__global__ __launch_bounds__(256) void head_kernel(
    const float* __restrict__ feat,
    const float* __restrict__ w1, const float* __restrict__ b1, const float* __restrict__ a1,
    const float* __restrict__ w2, const float* __restrict__ b2, const float* __restrict__ a2,
    const float* __restrict__ w3, const float* __restrict__ b3,
    float* __restrict__ out)
{
  int b = blockIdx.x, t = threadIdx.x;
  __shared__ float frow[512];
  __shared__ float z1[200];
  __shared__ float z2[80];
  frow[t] = feat[b * 512 + t];
  frow[256 + t] = feat[b * 512 + 256 + t];
  __syncthreads();
  if (t < 200) {
    float acc = b1[t];
#pragma unroll 8
    for (int k = 0; k < 512; k++) acc += frow[k] * w1[k * 200 + t];
    z1[t] = acc > 0.f ? acc : a1[t] * acc;
  }
  __syncthreads();
  if (t < 80) {
    float acc = b2[t];
#pragma unroll 8
    for (int k = 0; k < 200; k++) acc += z1[k] * w2[k * 80 + t];
    z2[t] = acc > 0.f ? acc : a2[t] * acc;
  }
  __syncthreads();
  if (t == 0) {
    float l0 = b3[0], l1 = b3[1];
    for (int k = 0; k < 80; k++) {
      float z = z2[k];
      l0 += z * w3[k * 2];
      l1 += z * w3[k * 2 + 1];
    }
    float m = fmaxf(l0, l1);
    float e0 = __expf(l0 - m), e1 = __expf(l1 - m);
    out[b * 2 + 0] = e0 / (e0 + e1);
    out[b * 2 + 1] = e1 / (e0 + e1);
  }
}

// ---------------------------------------------------------------- launch
extern "C" void kernel_launch(void* const* d_in, const int* in_sizes, int n_in,
                              void* d_out, int out_size, void* d_ws, size_t ws_size,
                              hipStream_t stream)
{
  const float* item_eb = (const float*)d_in[0];
  const float* his     = (const float*)d_in[1];
  const float* Wg1     = (const float*)d_in[2];
  const float* bg1     = (const float*)d_in[3];
  const float* Wc1     = (const float*)d_in[4];
  const float* bc1     = (const float*)d_in[5];
  const float* aw1     = (const float*)d_in[6];
  const float* ab1     = (const float*)d_in[7];
  const float* aw2     = (const float*)d_in[8];
  const float* ab2     = (const float*)d_in[9];
  const float* aw3     = (const float*)d_in[10];
  const float* ab3     = (const float*)d_in[11];
  const float* Wg2     = (const float*)d_in[12];
  const float* bg2     = (const float*)d_in[13];
  const float* Wc2     = (const float*)d_in[14];
  const float* bc2     = (const float*)d_in[15];
  const float* fc1w    = (const float*)d_in[16];
  const float* fc1b    = (const float*)d_in[17];
  const float* al1     = (const float*)d_in[18];
  const float* fc2w    = (const float*)d_in[19];
  const float* fc2b    = (const float*)d_in[20];
  const float* al2     = (const float*)d_in[21];
  const float* fc3w    = (const float*)d_in[22];
  const float* fc3b    = (const float*)d_in[23];
  const int*   seqlen  = (const int*)d_in[24];

  // ---- workspace layout (~74.8 MB peak)
  char* ws = (char*)d_ws;
  unsigned short* XhA    = (unsigned short*)(ws + 0L);           // 26,214,400: Xh_t, later din chunk
  unsigned short* xprojC = (unsigned short*)(ws + 26214400L);    // 19,660,800 f16; att h1/h2 overlay
  unsigned short* h1C    = (unsigned short*)(ws + 26214400L);    //  6,553,600 (overlay)
  unsigned short* h2C    = (unsigned short*)(ws + 32768000L);    //  6,553,600 (overlay)
  unsigned short* rnn1   = (unsigned short*)(ws + 45875200L);    // 26,214,400
  float*          scores = (float*)(ws + 72089600L);             //    409,600
  float*          alphas = (float*)(ws + 72499200L);             //    409,600
  float*          hstate = (float*)(ws + 72908800L);             //    262,144
  float*          feat   = (float*)(ws + 73170944L);             //  1,048,576
  unsigned int*   WgP1   = (unsigned int*)(ws + 74219520L);      //     65,536
  unsigned int*   WcP1   = (unsigned int*)(ws + 74285056L);      //     32,768
  unsigned int*   WgP2   = (unsigned int*)(ws + 74317824L);      //     65,536
  unsigned int*   WcP2   = (unsigned int*)(ws + 74383360L);      //     32,768
  unsigned short* W1xT   = (unsigned short*)(ws + 74416128L);    //     98,304
  unsigned short* W2xT   = (unsigned short*)(ws + 74514432L);    //     98,304
  unsigned short* AW1T   = (unsigned short*)(ws + 74612736L);    //    131,072
  unsigned short* AW2T   = (unsigned short*)(ws + 74743808L);    //     32,768
  float*          b384_1 = (float*)(ws + 74776576L);             //      1,536
  float*          b384_2 = (float*)(ws + 74778112L);             //      1,536
  float*          bA1    = (float*)(ws + 74779648L);             //        512
  float*          bA2    = (float*)(ws + 74780160L);             //        512

  const size_t chunkRows = (size_t)TC * 512;                     // 25600

  prep_weights<<<256, 256, 0, stream>>>(Wg1, Wc1, Wg2, Wc2, aw1, aw2, bg1, bc1,
                                        bg2, bc2, ab1, ab2,
                                        W1xT, W2xT, AW1T, AW2T, b384_1, b384_2, bA1, bA2,
                                        WgP1, WcP1, WgP2, WcP2);
  cast_his_t<<<12800, 256, 0, stream>>>((const float4*)his, (ushort4*)XhA);
  zero_f<<<256, 256, 0, stream>>>(hstate, 65536);

  // ---- GRU1 over chunks
  for (int c = 0; c < NC; c++) {
    gemm_bt<2><<<dim3(200, 3), 256, 0, stream>>>(XhA + c * chunkRows * 128, W1xT,
                                                 b384_1, nullptr, xprojC, 128, 384);
    gru_chunk<0><<<512, 256, 0, stream>>>(xprojC, WgP1, WcP1, seqlen, nullptr,
                                          rnn1, hstate, c * TC);
  }

  // ---- DIN attention over chunks (XhA reused as din; h1/h2 overlay xprojC)
  for (int c = 0; c < NC; c++) {
    build_din<<<3200, 256, 0, stream>>>(item_eb, rnn1, (ushort4*)XhA, (int)(c * chunkRows));
    gemm_bt<1><<<dim3(200, 1), 256, 0, stream>>>(XhA, AW1T, bA1, nullptr, h1C, 512, 128);
    gemm_bt<1><<<dim3(200, 1), 256, 0, stream>>>(h1C, AW2T, bA2, nullptr, h2C, 128, 128);
    scorer<<<100, 256, 0, stream>>>(h2C, aw3, ab3, scores, c * TC);
  }
  mask_softmax<<<512, 256, 0, stream>>>(scores, seqlen, alphas);

  // ---- AUGRU over chunks
  zero_f<<<256, 256, 0, stream>>>(hstate, 65536);
  for (int c = 0; c < NC; c++) {
    gemm_bt<2><<<dim3(200, 3), 256, 0, stream>>>(rnn1 + c * chunkRows * 128, W2xT,
                                                 b384_2, nullptr, xprojC, 128, 384);
    gru_chunk<1><<<512, 256, 0, stream>>>(xprojC, WgP2, WcP2, seqlen, alphas,
                                          nullptr, hstate, c * TC);
  }

  feat_kernel<<<512, 128, 0, stream>>>(item_eb, his, seqlen, hstate, feat);
  head_kernel<<<512, 256, 0, stream>>>(feat, fc1w, fc1b, al1, fc2w, fc2b, al2,
                                       fc3w, fc3b, (float*)d_out);
}

// Round 5
// 677.380 us; speedup vs baseline: 2.3213x; 1.0986x over previous
//
#include <hip/hip_runtime.h>
#include <hip/hip_bf16.h>

// DIEN (DIN_V2_Gru_Vec_attGru) forward. B=512, T=200, D=128, H=128.
// Round 5: fat kernels (GRU rows + backfill GEMM tiles in one launch),
// inline-asm v_dot2_f32_f16, 2-deep x-preact prefetch, double-buffered f16
// xproj (NC=4), din fused into att-gemm1 staging, scorer fused into
// att-gemm2 epilogue, feat fused into head. 16 launches total.

typedef __attribute__((ext_vector_type(8))) short bf16x8;
typedef __attribute__((ext_vector_type(4))) float f32x4;
typedef _Float16 f16x2 __attribute__((ext_vector_type(2)));

#define NC 4
#define TC 50
#define CROWS 25600          // TC*512 rows per chunk
#define CSH 3276800          // CROWS*128 shorts per chunk (rnn1/h1/XhA)

static __device__ __forceinline__ unsigned short f2bf(float f) {
  union { __hip_bfloat16 h; unsigned short u; } v;
  v.h = __float2bfloat16(f);
  return v.u;
}
static __device__ __forceinline__ float bf2f(unsigned short u) {
  union { __hip_bfloat16 h; unsigned short u; } v;
  v.u = u;
  return __bfloat162float(v.h);
}
static __device__ __forceinline__ unsigned short f2h(float f) {
  union { _Float16 h; unsigned short u; } v;
  v.h = (_Float16)f;
  return v.u;
}
static __device__ __forceinline__ float h2f(unsigned short u) {
  union { unsigned short u; _Float16 h; } v;
  v.u = u;
  return (float)v.h;
}
static __device__ __forceinline__ unsigned int pkf16(float a, float b) {
  union { f16x2 v; unsigned int u; } c;
  c.v = (f16x2){(_Float16)a, (_Float16)b};
  return c.u;
}
static __device__ __forceinline__ void dot2a(float& acc, unsigned int w, unsigned int h) {
  asm volatile("v_dot2_f32_f16 %0, %1, %2, %0" : "+v"(acc) : "v"(w), "v"(h));
}

// ---------------------------------------------------------------- prep
__global__ __launch_bounds__(256) void prep_weights(
    const float* __restrict__ item_eb,
    const float* __restrict__ Wg1, const float* __restrict__ Wc1,
    const float* __restrict__ Wg2, const float* __restrict__ Wc2,
    const float* __restrict__ aw1, const float* __restrict__ aw2,
    const float* __restrict__ aw3,
    const float* __restrict__ bg1, const float* __restrict__ bc1,
    const float* __restrict__ bg2, const float* __restrict__ bc2,
    const float* __restrict__ ab1, const float* __restrict__ ab2,
    unsigned short* __restrict__ W1xT, unsigned short* __restrict__ W2xT,
    unsigned short* __restrict__ AW1T, unsigned short* __restrict__ AW2T,
    float* __restrict__ b384_1, float* __restrict__ b384_2,
    float* __restrict__ bA1, float* __restrict__ bA2,
    unsigned int* __restrict__ WgP1, unsigned int* __restrict__ WcP1,
    unsigned int* __restrict__ WgP2, unsigned int* __restrict__ WcP2,
    float* __restrict__ w3p, unsigned short* __restrict__ Xq,
    float* __restrict__ hstate)
{
  int e = blockIdx.x * 256 + threadIdx.x;
  if (e < 49152) {              // W1xT/W2xT: [384 n][128 k]
    int n = e >> 7, k = e & 127;
    float v1 = (n < 256) ? Wg1[k * 256 + n] : Wc1[k * 128 + (n - 256)];
    float v2 = (n < 256) ? Wg2[k * 256 + n] : Wc2[k * 128 + (n - 256)];
    W1xT[e] = f2bf(v1);
    W2xT[e] = f2bf(v2);
  }
  if (e < 65536) {              // AW1T: [128 n][512 k], pad n>=80
    int n = e >> 9, k = e & 511;
    AW1T[e] = f2bf(n < 80 ? aw1[k * 80 + n] : 0.f);
    Xq[e] = f2bf(item_eb[e]);   // bf16 item_eb [512][128]
    hstate[e] = 0.f;
  }
  if (e < 16384) {              // AW2T: [128 n][128 k]
    int n = e >> 7, k = e & 127;
    AW2T[e] = f2bf((n < 40 && k < 80) ? aw2[k * 40 + n] : 0.f);
  }
  if (e < 16384) {              // WgP: [64 i][256 t], thread t owns gate col t
    int i = e >> 8, tt = e & 255;
    int row = 128 + 2 * i;
    WgP1[e] = pkf16(Wg1[row * 256 + tt], Wg1[(row + 1) * 256 + tt]);
    WgP2[e] = pkf16(Wg2[row * 256 + tt], Wg2[(row + 1) * 256 + tt]);
  }
  if (e < 8192) {               // WcP: [32 i][256 t], thread t: col t>>1, half t&1
    int i = e >> 8, tt = e & 255;
    int jc = tt >> 1, half = tt & 1;
    int row = 128 + half * 64 + 2 * i;
    WcP1[e] = pkf16(Wc1[row * 128 + jc], Wc1[(row + 1) * 128 + jc]);
    WcP2[e] = pkf16(Wc2[row * 128 + jc], Wc2[(row + 1) * 128 + jc]);
  }
  if (e < 384) {
    b384_1[e] = (e < 256) ? bg1[e] : bc1[e - 256];
    b384_2[e] = (e < 256) ? bg2[e] : bc2[e - 256];
  }
  if (e < 128) {
    bA1[e] = (e < 80) ? ab1[e] : 0.f;
    bA2[e] = (e < 40) ? ab2[e] : 0.f;
    w3p[e] = (e < 40) ? aw3[e] : 0.f;
  }
}

// ---------------------------------------------------------------- cast his -> bf16 t-major
__global__ __launch_bounds__(256) void cast_his_t(const float4* __restrict__ in4,
                                                  ushort4* __restrict__ out4)
{
  int i = blockIdx.x * 256 + threadIdx.x;
  float4 v = in4[i];
  int d4 = (i & 31) << 2;
  int bt = i >> 5;
  int tt = bt % 200, bb = bt / 200;
  out4[(((size_t)tt * 512 + bb) * 128 + d4) >> 2] =
      make_ushort4(f2bf(v.x), f2bf(v.y), f2bf(v.z), f2bf(v.w));
}

// ---------------------------------------------------------------- gemm body
// SRC 0: plain bf16 A. SRC 1: din on-the-fly [q|r|q-r|q*r], K=512.
// EPI 0: f16 out (+bias). EPI 1: bf16 sigmoid out. EPI 2: sigmoid+scorer->scores.
struct GemmP {
  const unsigned short* A;
  const unsigned short* B;
  const float* bias;
  unsigned short* out;
  float* scores;
  const float* w3p;
  const float* b3;
  const unsigned short* Xq;
  const unsigned short* rnn1;
  long rowbase;
  int K, ldc, mtiles, tbase;
};

static __device__ __forceinline__ uint4 bfop(uint4 q, uint4 r, bool mul) {
  unsigned short* qs = (unsigned short*)&q;
  unsigned short* rs = (unsigned short*)&r;
  uint4 o;
  unsigned short* os = (unsigned short*)&o;
#pragma unroll
  for (int i = 0; i < 8; i++) {
    float a = bf2f(qs[i]), b = bf2f(rs[i]);
    os[i] = f2bf(mul ? a * b : a - b);
  }
  return o;
}

template <int SRC, int EPI>
__device__ __forceinline__ void gemm_body(const GemmP& P, int tile, char* smem) {
  uint4* AsB = (uint4*)smem;         // 16 KB
  uint4* BsB = AsB + 1024;           // 16 KB
  const int tid = threadIdx.x;
  const int w = tid >> 6, l = tid & 63;
  const int mb = tile % P.mtiles, nb = tile / P.mtiles;
  const long mBase = (long)mb * 128;
  const int nBase = nb * 128;

  f32x4 acc[2][8];
#pragma unroll
  for (int m = 0; m < 2; m++)
#pragma unroll
    for (int n = 0; n < 8; n++) acc[m][n] = 0.f;

  const int srow = (tid >> 3) & 31;
  const int scc = l & 7;
  const int KK = SRC ? 512 : P.K;

  for (int kb = 0; kb < KK; kb += 64) {
#pragma unroll
    for (int p = 0; p < 4; p++) {
      int row = p * 32 + srow;
      long grow = mBase + row;
      uint4 va;
      if (SRC == 0) {
        va = *(const uint4*)(P.A + (size_t)grow * KK + kb + scc * 8);
      } else {
        int seg = kb >> 7;
        int c0 = (kb & 127) + scc * 8;
        int b = (int)(grow & 511);
        if (seg == 0) {
          va = *(const uint4*)(P.Xq + b * 128 + c0);
        } else if (seg == 1) {
          va = *(const uint4*)(P.rnn1 + (size_t)(P.rowbase + grow) * 128 + c0);
        } else {
          uint4 vq = *(const uint4*)(P.Xq + b * 128 + c0);
          uint4 vr = *(const uint4*)(P.rnn1 + (size_t)(P.rowbase + grow) * 128 + c0);
          va = bfop(vq, vr, seg == 3);
        }
      }
      uint4 vb = *(const uint4*)(P.B + (size_t)(nBase + row) * KK + kb + scc * 8);
      AsB[row * 8 + (scc ^ (row & 7))] = va;
      BsB[row * 8 + (scc ^ (row & 7))] = vb;
    }
    __syncthreads();
#pragma unroll
    for (int ks = 0; ks < 2; ks++) {
      int ccr = ks * 4 + (l >> 4);
      int r0 = w * 32 + (l & 15);
      int r1 = r0 + 16;
      bf16x8 a0 = *(const bf16x8*)&AsB[r0 * 8 + (ccr ^ (r0 & 7))];
      bf16x8 a1 = *(const bf16x8*)&AsB[r1 * 8 + (ccr ^ (r1 & 7))];
#pragma unroll
      for (int n = 0; n < 8; n++) {
        int rb = n * 16 + (l & 15);
        bf16x8 bn = *(const bf16x8*)&BsB[rb * 8 + (ccr ^ (rb & 7))];
        acc[0][n] = __builtin_amdgcn_mfma_f32_16x16x32_bf16(a0, bn, acc[0][n], 0, 0, 0);
        acc[1][n] = __builtin_amdgcn_mfma_f32_16x16x32_bf16(a1, bn, acc[1][n], 0, 0, 0);
      }
    }
    __syncthreads();
  }

  const int lcol = l & 15, lrow4 = (l >> 4) * 4;
  if (EPI == 2) {
    float sp[2][4] = {{0.f, 0.f, 0.f, 0.f}, {0.f, 0.f, 0.f, 0.f}};
#pragma unroll
    for (int n = 0; n < 8; n++) {
      int gcol = n * 16 + lcol;
      float bb = P.bias[gcol];
      float w3 = P.w3p[gcol];
#pragma unroll
      for (int m = 0; m < 2; m++)
#pragma unroll
        for (int i = 0; i < 4; i++) {
          float v = acc[m][n][i] + bb;
          sp[m][i] += w3 / (1.f + __expf(-v));
        }
    }
#pragma unroll
    for (int msk = 1; msk < 16; msk <<= 1)
#pragma unroll
      for (int m = 0; m < 2; m++)
#pragma unroll
        for (int i = 0; i < 4; i++) sp[m][i] += __shfl_xor(sp[m][i], msk);
    float b3v = P.b3[0];
    if (lcol == 0) {
#pragma unroll
      for (int m = 0; m < 2; m++)
#pragma unroll
        for (int i = 0; i < 4; i++) {
          long grow = mBase + w * 32 + m * 16 + lrow4 + i;
          int b = (int)(grow & 511);
          int tp = (int)(grow >> 9) + P.tbase;
          P.scores[b * 200 + tp] = sp[m][i] + b3v;
        }
    }
  } else {
#pragma unroll
    for (int n = 0; n < 8; n++) {
      int gcol = nBase + n * 16 + lcol;
      float bb = P.bias[gcol];
#pragma unroll
      for (int m = 0; m < 2; m++)
#pragma unroll
        for (int i = 0; i < 4; i++) {
          long grow = mBase + w * 32 + m * 16 + lrow4 + i;
          float v = acc[m][n][i] + bb;
          if (EPI == 0) P.out[grow * P.ldc + gcol] = f2h(v);
          else          P.out[grow * P.ldc + gcol] = f2bf(1.f / (1.f + __expf(-v)));
        }
    }
  }
}

// ---------------------------------------------------------------- gru body
// 1 row/block, 256 threads. Gate col t per thread (wg[64] f16x2 words in VGPR),
// cand col t>>1 half t&1 (wc[32]). 2-deep x-preact prefetch. Early exit.
struct GruP {
  const unsigned short* xproj;   // f16 [TC][512][384]
  const unsigned int* WgP;
  const unsigned int* WcP;
  const int* seqlen;
  const float* alphas;
  unsigned short* outbf;         // bf16 [T][512][128] (GRU1)
  float* hstate;
  int tbase;
};

template <int AUGRU>
__device__ void gru_body(const GruP& P, int r, char* smem) {
  float* hF = (float*)smem;                      // 128
  float* uF = hF + 128;                          // 128
  unsigned int* hH = (unsigned int*)(uF + 128);  // 64
  unsigned int* rghP = hH + 64;                  // 64
  const int t = threadIdx.x;
  const int jc = t >> 1;
  const int len = P.seqlen[r];
  int nsteps = len - P.tbase;
  if (nsteps > TC) nsteps = TC;

  if (nsteps <= 0) {
    if (!AUGRU && t < 64) {
      for (int s = 0; s < TC; s++)
        ((unsigned int*)(P.outbf + ((size_t)(P.tbase + s) * 512 + r) * 128))[t] = 0;
    }
    return;
  }
  __builtin_amdgcn_s_setprio(1);

  unsigned int wg[64], wc[32];
#pragma unroll
  for (int i = 0; i < 64; i++) wg[i] = P.WgP[i * 256 + t];
#pragma unroll
  for (int i = 0; i < 32; i++) wc[i] = P.WcP[i * 256 + t];

  if (t < 128) hF[t] = P.hstate[r * 128 + t];
  if (t < 64) hH[t] = pkf16(P.hstate[r * 128 + 2 * t], P.hstate[r * 128 + 2 * t + 1]);
  __syncthreads();

  const unsigned short* xp = P.xproj;
  const size_t RS = (size_t)512 * 384;
  const size_t base = (size_t)r * 384;
  unsigned short gA = xp[base + t], cA = xp[base + 256 + jc];
  int s1 = nsteps > 1 ? 1 : 0;
  unsigned short gB = xp[s1 * RS + base + t], cB = xp[s1 * RS + base + 256 + jc];
  float alA = AUGRU ? P.alphas[r * 200 + P.tbase] : 0.f;
  float alB = AUGRU ? P.alphas[r * 200 + P.tbase + s1] : 0.f;

  for (int ts = 0; ts < nsteps; ++ts) {
    int tsn = (ts + 2 < nsteps) ? ts + 2 : nsteps - 1;
    size_t off = (size_t)tsn * RS + base;
    unsigned short gC = xp[off + t];
    unsigned short cC = xp[off + 256 + jc];
    float alC = AUGRU ? P.alphas[r * 200 + P.tbase + tsn] : 0.f;

    // ---- gates (full col per thread, 4 split accumulators, dot2 asm)
    float a0 = 0.f, a1 = 0.f, a2 = 0.f, a3 = 0.f;
#pragma unroll
    for (int q = 0; q < 4; q++) {
      uint4 h0 = *(const uint4*)&hH[q * 16 + 0];
      uint4 h1 = *(const uint4*)&hH[q * 16 + 4];
      uint4 h2 = *(const uint4*)&hH[q * 16 + 8];
      uint4 h3 = *(const uint4*)&hH[q * 16 + 12];
      dot2a(a0, wg[q * 16 + 0], h0.x);  dot2a(a1, wg[q * 16 + 1], h0.y);
      dot2a(a2, wg[q * 16 + 2], h0.z);  dot2a(a3, wg[q * 16 + 3], h0.w);
      dot2a(a0, wg[q * 16 + 4], h1.x);  dot2a(a1, wg[q * 16 + 5], h1.y);
      dot2a(a2, wg[q * 16 + 6], h1.z);  dot2a(a3, wg[q * 16 + 7], h1.w);
      dot2a(a0, wg[q * 16 + 8], h2.x);  dot2a(a1, wg[q * 16 + 9], h2.y);
      dot2a(a2, wg[q * 16 + 10], h2.z); dot2a(a3, wg[q * 16 + 11], h2.w);
      dot2a(a0, wg[q * 16 + 12], h3.x); dot2a(a1, wg[q * 16 + 13], h3.y);
      dot2a(a2, wg[q * 16 + 14], h3.z); dot2a(a3, wg[q * 16 + 15], h3.w);
    }
    float a = (a0 + a1) + (a2 + a3) + h2f(gA);
    float g = 1.f / (1.f + __expf(-a));
    if (t < 128) {
      float rgh = g * hF[t];
      float rh2 = __shfl_down(rgh, 1);
      if (!(t & 1)) rghP[t >> 1] = pkf16(rgh, rh2);
    } else {
      uF[t - 128] = g;
    }
    __syncthreads();

    // ---- candidate + update
    float c0 = 0.f, c1 = 0.f;
    const uint4* rp = (const uint4*)&rghP[(t & 1) * 32];
#pragma unroll
    for (int q = 0; q < 8; q++) {
      uint4 rq = rp[q];
      dot2a(c0, wc[q * 4 + 0], rq.x);
      dot2a(c1, wc[q * 4 + 1], rq.y);
      dot2a(c0, wc[q * 4 + 2], rq.z);
      dot2a(c1, wc[q * 4 + 3], rq.w);
    }
    float c = c0 + c1;
    c += __shfl_xor(c, 1);
    c += h2f(cA);
    c = fminf(fmaxf(c, -15.f), 15.f);
    float e2 = __expf(2.f * c);
    c = 1.f - 2.f / (e2 + 1.f);          // tanh
    float u = uF[jc];
    if (AUGRU) u *= (1.f - alA);
    float h = hF[jc];
    float hn = u * h + (1.f - u) * c;
    float hnHi = __shfl_down(hn, 2);
    if (!(t & 1)) {
      hF[jc] = hn;
      if (!AUGRU) P.outbf[((size_t)(P.tbase + ts) * 512 + r) * 128 + jc] = f2bf(hn);
    }
    if (!(t & 3)) hH[t >> 2] = pkf16(hn, hnHi);
    __syncthreads();

    gA = gB; cA = cB; alA = alB;
    gB = gC; cB = cC; alB = alC;
  }

  if (t < 128) P.hstate[r * 128 + t] = hF[t];
  if (!AUGRU && nsteps < TC && t < 64) {
    for (int s = nsteps; s < TC; s++)
      ((unsigned int*)(P.outbf + ((size_t)(P.tbase + s) * 512 + r) * 128))[t] = 0;
  }
}

// ---------------------------------------------------------------- fat kernel
template <int AUG, int GRU, int S1, int E1, int S2, int E2, int S3, int E3>
__global__ __launch_bounds__(256) void fatk(GruP gp, GemmP p1, int c1,
                                            GemmP p2, int c2, GemmP p3)
{
  extern __shared__ char smem[];
  int id = blockIdx.x;
  if constexpr (GRU) {
    if (id < 512) { gru_body<AUG>(gp, id, smem); return; }
    id -= 512;
  }
  if constexpr (S1 >= 0) {
    if (id < c1) { gemm_body<S1, E1>(p1, id, smem); return; }
    id -= c1;
  }
  if constexpr (S2 >= 0) {
    if (id < c2) { gemm_body<S2, E2>(p2, id, smem); return; }
    id -= c2;
  }
  if constexpr (S3 >= 0) gemm_body<S3, E3>(p3, id, smem);
}

// ---------------------------------------------------------------- masked softmax (+zero hstate)
__global__ __launch_bounds__(256) void mask_softmax(
    const float* __restrict__ scores, const int* __restrict__ seqlen,
    float* __restrict__ alphas, float* __restrict__ hstate)
{
  int b = blockIdx.x, t = threadIdx.x;
  __shared__ float red[256];
  if (t < 128) hstate[b * 128 + t] = 0.f;
  int len = seqlen[b];
  float s = (t < 200 && t < len) ? scores[b * 200 + t] : -1e30f;
  red[t] = s;
  __syncthreads();
  for (int o = 128; o > 0; o >>= 1) {
    if (t < o) red[t] = fmaxf(red[t], red[t + o]);
    __syncthreads();
  }
  float m = red[0];
  __syncthreads();
  float e = (t < 200 && t < len) ? __expf(s - m) : 0.f;
  red[t] = e;
  __syncthreads();
  for (int o = 128; o > 0; o >>= 1) {
    if (t < o) red[t] += red[t + o];
    __syncthreads();
  }
  float denom = red[0];
  if (t < 200) alphas[b * 200 + t] = e / denom;
}

// ---------------------------------------------------------------- head (his_sum fused)
__global__ __launch_bounds__(256) void head_kernel(
    const float* __restrict__ item_eb, const float* __restrict__ his,
    const int* __restrict__ seqlen, const float* __restrict__ hstate,
    const float* __restrict__ w1, const float* __restrict__ b1, const float* __restrict__ a1,
    const float* __restrict__ w2, const float* __restrict__ b2, const float* __restrict__ a2,
    const float* __restrict__ w3, const float* __restrict__ b3,
    float* __restrict__ out)
{
  int b = blockIdx.x, t = threadIdx.x;
  __shared__ float frow[512];
  __shared__ float z1[200];
  __shared__ float z2[80];
  __shared__ float hs2[256];
  int len = seqlen[b];
  int col = t & 127, hf = t >> 7;
  float s = 0.f;
  for (int ts = hf; ts < len; ts += 2) s += his[((size_t)b * 200 + ts) * 128 + col];
  hs2[t] = s;
  __syncthreads();
  if (t < 128) {
    float sv = hs2[t] + hs2[t + 128];
    float q = item_eb[b * 128 + t];
    frow[t] = q;
    frow[128 + t] = sv;
    frow[256 + t] = q * sv;
    frow[384 + t] = hstate[b * 128 + t];
  }
  __syncthreads();
  if (t < 200) {
    float acc = b1[t];
#pragma unroll 8
    for (int k = 0; k < 512; k++) acc += frow[k] * w1[k * 200 + t];
    z1[t] = acc > 0.f ? acc : a1[t] * acc;
  }
  __syncthreads();
  if (t < 80) {
    float acc = b2[t];
#pragma unroll 8
    for (int k = 0; k < 200; k++) acc += z1[k] * w2[k * 80 + t];
    z2[t] = acc > 0.f ? acc : a2[t] * acc;
  }
  __syncthreads();
  if (t == 0) {
    float l0 = b3[0], l1 = b3[1];
    for (int k = 0; k < 80; k++) {
      float z = z2[k];
      l0 += z * w3[k * 2];
      l1 += z * w3[k * 2 + 1];
    }
    float m = fmaxf(l0, l1);
    float e0 = __expf(l0 - m), e1 = __expf(l1 - m);
    out[b * 2 + 0] = e0 / (e0 + e1);
    out[b * 2 + 1] = e1 / (e0 + e1);
  }
}

// ---------------------------------------------------------------- launch
extern "C" void kernel_launch(void* const* d_in, const int* in_sizes, int n_in,
                              void* d_out, int out_size, void* d_ws, size_t ws_size,
                              hipStream_t stream)
{
  const float* item_eb = (const float*)d_in[0];
  const float* his     = (const float*)d_in[1];
  const float* Wg1     = (const float*)d_in[2];
  const float* bg1     = (const float*)d_in[3];
  const float* Wc1     = (const float*)d_in[4];
  const float* bc1     = (const float*)d_in[5];
  const float* aw1     = (const float*)d_in[6];
  const float* ab1     = (const float*)d_in[7];
  const float* aw2     = (const float*)d_in[8];
  const float* ab2     = (const float*)d_in[9];
  const float* aw3     = (const float*)d_in[10];
  const float* ab3     = (const float*)d_in[11];
  const float* Wg2     = (const float*)d_in[12];
  const float* bg2     = (const float*)d_in[13];
  const float* Wc2     = (const float*)d_in[14];
  const float* bc2     = (const float*)d_in[15];
  const float* fc1w    = (const float*)d_in[16];
  const float* fc1b    = (const float*)d_in[17];
  const float* al1     = (const float*)d_in[18];
  const float* fc2w    = (const float*)d_in[19];
  const float* fc2b    = (const float*)d_in[20];
  const float* al2     = (const float*)d_in[21];
  const float* fc3w    = (const float*)d_in[22];
  const float* fc3b    = (const float*)d_in[23];
  const int*   seqlen  = (const int*)d_in[24];

  // ---- workspace layout (~93.5 MB; round-2 proved >=94.24 MB available)
  char* ws = (char*)d_ws;
  unsigned short* XhA    = (unsigned short*)(ws + 0L);         // 26,214,400 his bf16 t-major; later h1 ring
  unsigned short* xpA    = (unsigned short*)(ws + 26214400L);  // 19,660,800 f16 xproj buf A
  unsigned short* xpB    = (unsigned short*)(ws + 45875200L);  // 19,660,800 f16 xproj buf B
  unsigned short* rnn1   = (unsigned short*)(ws + 65536000L);  // 26,214,400
  float*          scores = (float*)(ws + 91750400L);           //    409,600
  float*          alphas = (float*)(ws + 92160000L);           //    409,600
  float*          hstate = (float*)(ws + 92569600L);           //    262,144
  unsigned int*   WgP1   = (unsigned int*)(ws + 92831744L);    //     65,536
  unsigned int*   WcP1   = (unsigned int*)(ws + 92897280L);    //     32,768
  unsigned int*   WgP2   = (unsigned int*)(ws + 92930048L);    //     65,536
  unsigned int*   WcP2   = (unsigned int*)(ws + 92995584L);    //     32,768
  unsigned short* W1xT   = (unsigned short*)(ws + 93028352L);  //     98,304
  unsigned short* W2xT   = (unsigned short*)(ws + 93126656L);  //     98,304
  unsigned short* AW1T   = (unsigned short*)(ws + 93224960L);  //    131,072
  unsigned short* AW2T   = (unsigned short*)(ws + 93356032L);  //     32,768
  float*          b384_1 = (float*)(ws + 93388800L);           //      1,536
  float*          b384_2 = (float*)(ws + 93390336L);           //      1,536
  float*          bA1    = (float*)(ws + 93391872L);           //        512
  float*          bA2    = (float*)(ws + 93392384L);           //        512
  float*          w3p    = (float*)(ws + 93392896L);           //        512
  unsigned short* Xq     = (unsigned short*)(ws + 93393408L);  //    131,072

  unsigned short* h1[NC] = {XhA, XhA + CSH, XhA + 2 * CSH, XhA + 3 * CSH};

  const int SM = 32768;
  GruP gz{}; GemmP dz{};

  auto mkGru = [&](int c, int aug) {
    GruP g;
    g.xproj = (c & 1) ? xpB : xpA;
    g.WgP = aug ? WgP2 : WgP1; g.WcP = aug ? WcP2 : WcP1;
    g.seqlen = seqlen; g.alphas = alphas;
    g.outbf = aug ? nullptr : rnn1; g.hstate = hstate; g.tbase = c * TC;
    return g;
  };
  auto mkXp = [&](const unsigned short* A, const float* bias, unsigned short* outp) {
    GemmP p{}; p.A = A; p.B = (bias == b384_1) ? W1xT : W2xT; p.bias = bias;
    p.out = outp; p.K = 128; p.ldc = 384; p.mtiles = 200; return p;
  };
  auto mkAtt1 = [&](int c) {
    GemmP p{}; p.B = AW1T; p.bias = bA1; p.out = h1[c];
    p.Xq = Xq; p.rnn1 = rnn1; p.rowbase = (long)c * CROWS;
    p.K = 512; p.ldc = 128; p.mtiles = 200; return p;
  };
  auto mkAtt2 = [&](int c) {
    GemmP p{}; p.A = h1[c]; p.B = AW2T; p.bias = bA2;
    p.scores = scores; p.w3p = w3p; p.b3 = ab3;
    p.K = 128; p.ldc = 128; p.mtiles = 200; p.tbase = c * TC; return p;
  };

  // L1/L2: prep + cast
  prep_weights<<<256, 256, 0, stream>>>(item_eb, Wg1, Wc1, Wg2, Wc2, aw1, aw2, aw3,
                                        bg1, bc1, bg2, bc2, ab1, ab2,
                                        W1xT, W2xT, AW1T, AW2T, b384_1, b384_2, bA1, bA2,
                                        WgP1, WcP1, WgP2, WcP2, w3p, Xq, hstate);
  cast_his_t<<<12800, 256, 0, stream>>>((const float4*)his, (ushort4*)XhA);

  // L3: xproj1-c0 -> xpA
  fatk<0,0, 0,0, -1,0, -1,0><<<600, 256, SM, stream>>>(
      gz, mkXp(XhA, b384_1, xpA), 600, dz, 0, dz);
  // L4: gru1-c0 | xproj1-c1 -> xpB
  fatk<0,1, 0,0, -1,0, -1,0><<<1112, 256, SM, stream>>>(
      mkGru(0,0), mkXp(XhA + (size_t)CSH, b384_1, xpB), 600, dz, 0, dz);
  // L5: gru1-c1 | xproj1-c2 -> xpA
  fatk<0,1, 0,0, -1,0, -1,0><<<1112, 256, SM, stream>>>(
      mkGru(1,0), mkXp(XhA + (size_t)2*CSH, b384_1, xpA), 600, dz, 0, dz);
  // L6: gru1-c2 | xproj1-c3 -> xpB | att1-c0 -> h1[0]
  fatk<0,1, 0,0, 1,1, -1,0><<<1712, 256, SM, stream>>>(
      mkGru(2,0), mkXp(XhA + (size_t)3*CSH, b384_1, xpB), 600, mkAtt1(0), 200, dz);
  // L7: gru1-c3 | att1-c1 | att2-c0
  fatk<0,1, 1,1, 0,2, -1,0><<<912, 256, SM, stream>>>(
      mkGru(3,0), mkAtt1(1), 200, mkAtt2(0), 200, dz);
  // L8: att1-c2 | att2-c1 | augru-gemm-c0 -> xpA
  fatk<0,0, 1,1, 0,2, 0,0><<<1000, 256, SM, stream>>>(
      gz, mkAtt1(2), 200, mkAtt2(1), 200, mkXp(rnn1, b384_2, xpA));
  // L9: att1-c3 | att2-c2 | augru-gemm-c1 -> xpB
  fatk<0,0, 1,1, 0,2, 0,0><<<1000, 256, SM, stream>>>(
      gz, mkAtt1(3), 200, mkAtt2(2), 200, mkXp(rnn1 + (size_t)CSH, b384_2, xpB));
  // L10: att2-c3
  fatk<0,0, 0,2, -1,0, -1,0><<<200, 256, SM, stream>>>(
      gz, mkAtt2(3), 200, dz, 0, dz);
  // L11: softmax + zero hstate
  mask_softmax<<<512, 256, 0, stream>>>(scores, seqlen, alphas, hstate);
  // L12: augru-c0
  fatk<1,1, -1,0, -1,0, -1,0><<<512, 256, SM, stream>>>(
      mkGru(0,1), dz, 0, dz, 0, dz);
  // L13: augru-c1 | augru-gemm-c2 -> xpA
  fatk<1,1, 0,0, -1,0, -1,0><<<1112, 256, SM, stream>>>(
      mkGru(1,1), mkXp(rnn1 + (size_t)2*CSH, b384_2, xpA), 600, dz, 0, dz);
  // L14: augru-c2 | augru-gemm-c3 -> xpB
  fatk<1,1, 0,0, -1,0, -1,0><<<1112, 256, SM, stream>>>(
      mkGru(2,1), mkXp(rnn1 + (size_t)3*CSH, b384_2, xpB), 600, dz, 0, dz);
  // L15: augru-c3
  fatk<1,1, -1,0, -1,0, -1,0><<<512, 256, SM, stream>>>(
      mkGru(3,1), dz, 0, dz, 0, dz);
  // L16: head
  head_kernel<<<512, 256, 0, stream>>>(item_eb, his, seqlen, hstate,
                                       fc1w, fc1b, al1, fc2w, fc2b, al2,
                                       fc3w, fc3b, (float*)d_out);
}

// Round 6
// 664.245 us; speedup vs baseline: 2.3672x; 1.0198x over previous
//
#include <hip/hip_runtime.h>
#include <hip/hip_bf16.h>

// DIEN (DIN_V2_Gru_Vec_attGru) forward. B=512, T=200, D=128, H=128.
// Round 6: gru_body barriers -> lgkmcnt-only raw s_barrier (no vmcnt drain,
// keeps x-preact prefetch in flight across barriers); his_sum moved out of
// head into a backfill body co-launched with augru-c0.

typedef __attribute__((ext_vector_type(8))) short bf16x8;
typedef __attribute__((ext_vector_type(4))) float f32x4;
typedef _Float16 f16x2 __attribute__((ext_vector_type(2)));

#define NC 4
#define TC 50
#define CROWS 25600          // TC*512 rows per chunk
#define CSH 3276800          // CROWS*128 shorts per chunk (rnn1/h1/XhA)

static __device__ __forceinline__ unsigned short f2bf(float f) {
  union { __hip_bfloat16 h; unsigned short u; } v;
  v.h = __float2bfloat16(f);
  return v.u;
}
static __device__ __forceinline__ float bf2f(unsigned short u) {
  union { __hip_bfloat16 h; unsigned short u; } v;
  v.u = u;
  return __bfloat162float(v.h);
}
static __device__ __forceinline__ unsigned short f2h(float f) {
  union { _Float16 h; unsigned short u; } v;
  v.h = (_Float16)f;
  return v.u;
}
static __device__ __forceinline__ float h2f(unsigned short u) {
  union { unsigned short u; _Float16 h; } v;
  v.u = u;
  return (float)v.h;
}
static __device__ __forceinline__ unsigned int pkf16(float a, float b) {
  union { f16x2 v; unsigned int u; } c;
  c.v = (f16x2){(_Float16)a, (_Float16)b};
  return c.u;
}
static __device__ __forceinline__ void dot2a(float& acc, unsigned int w, unsigned int h) {
  asm volatile("v_dot2_f32_f16 %0, %1, %2, %0" : "+v"(acc) : "v"(w), "v"(h));
}
// LDS-only barrier: does NOT drain vmcnt, so global prefetches stay in flight.
static __device__ __forceinline__ void gbar() {
  __builtin_amdgcn_sched_barrier(0);
  asm volatile("s_waitcnt lgkmcnt(0)" ::: "memory");
  __builtin_amdgcn_s_barrier();
  __builtin_amdgcn_sched_barrier(0);
}

// ---------------------------------------------------------------- prep
__global__ __launch_bounds__(256) void prep_weights(
    const float* __restrict__ item_eb,
    const float* __restrict__ Wg1, const float* __restrict__ Wc1,
    const float* __restrict__ Wg2, const float* __restrict__ Wc2,
    const float* __restrict__ aw1, const float* __restrict__ aw2,
    const float* __restrict__ aw3,
    const float* __restrict__ bg1, const float* __restrict__ bc1,
    const float* __restrict__ bg2, const float* __restrict__ bc2,
    const float* __restrict__ ab1, const float* __restrict__ ab2,
    unsigned short* __restrict__ W1xT, unsigned short* __restrict__ W2xT,
    unsigned short* __restrict__ AW1T, unsigned short* __restrict__ AW2T,
    float* __restrict__ b384_1, float* __restrict__ b384_2,
    float* __restrict__ bA1, float* __restrict__ bA2,
    unsigned int* __restrict__ WgP1, unsigned int* __restrict__ WcP1,
    unsigned int* __restrict__ WgP2, unsigned int* __restrict__ WcP2,
    float* __restrict__ w3p, unsigned short* __restrict__ Xq,
    float* __restrict__ hstate)
{
  int e = blockIdx.x * 256 + threadIdx.x;
  if (e < 49152) {              // W1xT/W2xT: [384 n][128 k]
    int n = e >> 7, k = e & 127;
    float v1 = (n < 256) ? Wg1[k * 256 + n] : Wc1[k * 128 + (n - 256)];
    float v2 = (n < 256) ? Wg2[k * 256 + n] : Wc2[k * 128 + (n - 256)];
    W1xT[e] = f2bf(v1);
    W2xT[e] = f2bf(v2);
  }
  if (e < 65536) {              // AW1T: [128 n][512 k], pad n>=80
    int n = e >> 9, k = e & 511;
    AW1T[e] = f2bf(n < 80 ? aw1[k * 80 + n] : 0.f);
    Xq[e] = f2bf(item_eb[e]);   // bf16 item_eb [512][128]
    hstate[e] = 0.f;
  }
  if (e < 16384) {              // AW2T: [128 n][128 k]
    int n = e >> 7, k = e & 127;
    AW2T[e] = f2bf((n < 40 && k < 80) ? aw2[k * 40 + n] : 0.f);
  }
  if (e < 16384) {              // WgP: [64 i][256 t], thread t owns gate col t
    int i = e >> 8, tt = e & 255;
    int row = 128 + 2 * i;
    WgP1[e] = pkf16(Wg1[row * 256 + tt], Wg1[(row + 1) * 256 + tt]);
    WgP2[e] = pkf16(Wg2[row * 256 + tt], Wg2[(row + 1) * 256 + tt]);
  }
  if (e < 8192) {               // WcP: [32 i][256 t], thread t: col t>>1, half t&1
    int i = e >> 8, tt = e & 255;
    int jc = tt >> 1, half = tt & 1;
    int row = 128 + half * 64 + 2 * i;
    WcP1[e] = pkf16(Wc1[row * 128 + jc], Wc1[(row + 1) * 128 + jc]);
    WcP2[e] = pkf16(Wc2[row * 128 + jc], Wc2[(row + 1) * 128 + jc]);
  }
  if (e < 384) {
    b384_1[e] = (e < 256) ? bg1[e] : bc1[e - 256];
    b384_2[e] = (e < 256) ? bg2[e] : bc2[e - 256];
  }
  if (e < 128) {
    bA1[e] = (e < 80) ? ab1[e] : 0.f;
    bA2[e] = (e < 40) ? ab2[e] : 0.f;
    w3p[e] = (e < 40) ? aw3[e] : 0.f;
  }
}

// ---------------------------------------------------------------- cast his -> bf16 t-major
__global__ __launch_bounds__(256) void cast_his_t(const float4* __restrict__ in4,
                                                  ushort4* __restrict__ out4)
{
  int i = blockIdx.x * 256 + threadIdx.x;
  float4 v = in4[i];
  int d4 = (i & 31) << 2;
  int bt = i >> 5;
  int tt = bt % 200, bb = bt / 200;
  out4[(((size_t)tt * 512 + bb) * 128 + d4) >> 2] =
      make_ushort4(f2bf(v.x), f2bf(v.y), f2bf(v.z), f2bf(v.w));
}

// ---------------------------------------------------------------- gemm body
// SRC 0: plain bf16 A. SRC 1: din on-the-fly [q|r|q-r|q*r], K=512.
// EPI 0: f16 out (+bias). EPI 1: bf16 sigmoid out. EPI 2: sigmoid+scorer->scores.
struct GemmP {
  const unsigned short* A;
  const unsigned short* B;
  const float* bias;
  unsigned short* out;
  float* scores;
  const float* w3p;
  const float* b3;
  const unsigned short* Xq;
  const unsigned short* rnn1;
  long rowbase;
  int K, ldc, mtiles, tbase;
};

static __device__ __forceinline__ uint4 bfop(uint4 q, uint4 r, bool mul) {
  unsigned short* qs = (unsigned short*)&q;
  unsigned short* rs = (unsigned short*)&r;
  uint4 o;
  unsigned short* os = (unsigned short*)&o;
#pragma unroll
  for (int i = 0; i < 8; i++) {
    float a = bf2f(qs[i]), b = bf2f(rs[i]);
    os[i] = f2bf(mul ? a * b : a - b);
  }
  return o;
}

template <int SRC, int EPI>
__device__ __forceinline__ void gemm_body(const GemmP& P, int tile, char* smem) {
  uint4* AsB = (uint4*)smem;         // 16 KB
  uint4* BsB = AsB + 1024;           // 16 KB
  const int tid = threadIdx.x;
  const int w = tid >> 6, l = tid & 63;
  const int mb = tile % P.mtiles, nb = tile / P.mtiles;
  const long mBase = (long)mb * 128;
  const int nBase = nb * 128;

  f32x4 acc[2][8];
#pragma unroll
  for (int m = 0; m < 2; m++)
#pragma unroll
    for (int n = 0; n < 8; n++) acc[m][n] = 0.f;

  const int srow = (tid >> 3) & 31;
  const int scc = l & 7;
  const int KK = SRC ? 512 : P.K;

  for (int kb = 0; kb < KK; kb += 64) {
#pragma unroll
    for (int p = 0; p < 4; p++) {
      int row = p * 32 + srow;
      long grow = mBase + row;
      uint4 va;
      if (SRC == 0) {
        va = *(const uint4*)(P.A + (size_t)grow * KK + kb + scc * 8);
      } else {
        int seg = kb >> 7;
        int c0 = (kb & 127) + scc * 8;
        int b = (int)(grow & 511);
        if (seg == 0) {
          va = *(const uint4*)(P.Xq + b * 128 + c0);
        } else if (seg == 1) {
          va = *(const uint4*)(P.rnn1 + (size_t)(P.rowbase + grow) * 128 + c0);
        } else {
          uint4 vq = *(const uint4*)(P.Xq + b * 128 + c0);
          uint4 vr = *(const uint4*)(P.rnn1 + (size_t)(P.rowbase + grow) * 128 + c0);
          va = bfop(vq, vr, seg == 3);
        }
      }
      uint4 vb = *(const uint4*)(P.B + (size_t)(nBase + row) * KK + kb + scc * 8);
      AsB[row * 8 + (scc ^ (row & 7))] = va;
      BsB[row * 8 + (scc ^ (row & 7))] = vb;
    }
    __syncthreads();
#pragma unroll
    for (int ks = 0; ks < 2; ks++) {
      int ccr = ks * 4 + (l >> 4);
      int r0 = w * 32 + (l & 15);
      int r1 = r0 + 16;
      bf16x8 a0 = *(const bf16x8*)&AsB[r0 * 8 + (ccr ^ (r0 & 7))];
      bf16x8 a1 = *(const bf16x8*)&AsB[r1 * 8 + (ccr ^ (r1 & 7))];
#pragma unroll
      for (int n = 0; n < 8; n++) {
        int rb = n * 16 + (l & 15);
        bf16x8 bn = *(const bf16x8*)&BsB[rb * 8 + (ccr ^ (rb & 7))];
        acc[0][n] = __builtin_amdgcn_mfma_f32_16x16x32_bf16(a0, bn, acc[0][n], 0, 0, 0);
        acc[1][n] = __builtin_amdgcn_mfma_f32_16x16x32_bf16(a1, bn, acc[1][n], 0, 0, 0);
      }
    }
    __syncthreads();
  }

  const int lcol = l & 15, lrow4 = (l >> 4) * 4;
  if (EPI == 2) {
    float sp[2][4] = {{0.f, 0.f, 0.f, 0.f}, {0.f, 0.f, 0.f, 0.f}};
#pragma unroll
    for (int n = 0; n < 8; n++) {
      int gcol = n * 16 + lcol;
      float bb = P.bias[gcol];
      float w3 = P.w3p[gcol];
#pragma unroll
      for (int m = 0; m < 2; m++)
#pragma unroll
        for (int i = 0; i < 4; i++) {
          float v = acc[m][n][i] + bb;
          sp[m][i] += w3 / (1.f + __expf(-v));
        }
    }
#pragma unroll
    for (int msk = 1; msk < 16; msk <<= 1)
#pragma unroll
      for (int m = 0; m < 2; m++)
#pragma unroll
        for (int i = 0; i < 4; i++) sp[m][i] += __shfl_xor(sp[m][i], msk);
    float b3v = P.b3[0];
    if (lcol == 0) {
#pragma unroll
      for (int m = 0; m < 2; m++)
#pragma unroll
        for (int i = 0; i < 4; i++) {
          long grow = mBase + w * 32 + m * 16 + lrow4 + i;
          int b = (int)(grow & 511);
          int tp = (int)(grow >> 9) + P.tbase;
          P.scores[b * 200 + tp] = sp[m][i] + b3v;
        }
    }
  } else {
#pragma unroll
    for (int n = 0; n < 8; n++) {
      int gcol = nBase + n * 16 + lcol;
      float bb = P.bias[gcol];
#pragma unroll
      for (int m = 0; m < 2; m++)
#pragma unroll
        for (int i = 0; i < 4; i++) {
          long grow = mBase + w * 32 + m * 16 + lrow4 + i;
          float v = acc[m][n][i] + bb;
          if (EPI == 0) P.out[grow * P.ldc + gcol] = f2h(v);
          else          P.out[grow * P.ldc + gcol] = f2bf(1.f / (1.f + __expf(-v)));
        }
    }
  }
}

// ---------------------------------------------------------------- gru body
// 1 row/block, 256 threads. Gate col t per thread (wg[64] f16x2 words in VGPR),
// cand col t>>1 half t&1 (wc[32]). 2-deep x-preact prefetch. Early exit.
// Barriers are lgkm-only (gbar) so global prefetches survive across them.
struct GruP {
  const unsigned short* xproj;   // f16 [TC][512][384]
  const unsigned int* WgP;
  const unsigned int* WcP;
  const int* seqlen;
  const float* alphas;
  unsigned short* outbf;         // bf16 [T][512][128] (GRU1)
  float* hstate;
  int tbase;
};

template <int AUGRU>
__device__ void gru_body(const GruP& P, int r, char* smem) {
  float* hF = (float*)smem;                      // 128
  float* uF = hF + 128;                          // 128
  unsigned int* hH = (unsigned int*)(uF + 128);  // 64
  unsigned int* rghP = hH + 64;                  // 64
  const int t = threadIdx.x;
  const int jc = t >> 1;
  const int len = P.seqlen[r];
  int nsteps = len - P.tbase;
  if (nsteps > TC) nsteps = TC;

  if (nsteps <= 0) {
    if (!AUGRU && t < 64) {
      for (int s = 0; s < TC; s++)
        ((unsigned int*)(P.outbf + ((size_t)(P.tbase + s) * 512 + r) * 128))[t] = 0;
    }
    return;
  }
  __builtin_amdgcn_s_setprio(1);

  unsigned int wg[64], wc[32];
#pragma unroll
  for (int i = 0; i < 64; i++) wg[i] = P.WgP[i * 256 + t];
#pragma unroll
  for (int i = 0; i < 32; i++) wc[i] = P.WcP[i * 256 + t];

  if (t < 128) hF[t] = P.hstate[r * 128 + t];
  if (t < 64) hH[t] = pkf16(P.hstate[r * 128 + 2 * t], P.hstate[r * 128 + 2 * t + 1]);
  gbar();

  const unsigned short* xp = P.xproj;
  const size_t RS = (size_t)512 * 384;
  const size_t base = (size_t)r * 384;
  unsigned short gA = xp[base + t], cA = xp[base + 256 + jc];
  int s1 = nsteps > 1 ? 1 : 0;
  unsigned short gB = xp[s1 * RS + base + t], cB = xp[s1 * RS + base + 256 + jc];
  float alA = AUGRU ? P.alphas[r * 200 + P.tbase] : 0.f;
  float alB = AUGRU ? P.alphas[r * 200 + P.tbase + s1] : 0.f;

  for (int ts = 0; ts < nsteps; ++ts) {
    int tsn = (ts + 2 < nsteps) ? ts + 2 : nsteps - 1;
    size_t off = (size_t)tsn * RS + base;
    unsigned short gC = xp[off + t];
    unsigned short cC = xp[off + 256 + jc];
    float alC = AUGRU ? P.alphas[r * 200 + P.tbase + tsn] : 0.f;

    // ---- gates (full col per thread, 4 split accumulators, dot2 asm)
    float a0 = 0.f, a1 = 0.f, a2 = 0.f, a3 = 0.f;
#pragma unroll
    for (int q = 0; q < 4; q++) {
      uint4 h0 = *(const uint4*)&hH[q * 16 + 0];
      uint4 h1 = *(const uint4*)&hH[q * 16 + 4];
      uint4 h2 = *(const uint4*)&hH[q * 16 + 8];
      uint4 h3 = *(const uint4*)&hH[q * 16 + 12];
      dot2a(a0, wg[q * 16 + 0], h0.x);  dot2a(a1, wg[q * 16 + 1], h0.y);
      dot2a(a2, wg[q * 16 + 2], h0.z);  dot2a(a3, wg[q * 16 + 3], h0.w);
      dot2a(a0, wg[q * 16 + 4], h1.x);  dot2a(a1, wg[q * 16 + 5], h1.y);
      dot2a(a2, wg[q * 16 + 6], h1.z);  dot2a(a3, wg[q * 16 + 7], h1.w);
      dot2a(a0, wg[q * 16 + 8], h2.x);  dot2a(a1, wg[q * 16 + 9], h2.y);
      dot2a(a2, wg[q * 16 + 10], h2.z); dot2a(a3, wg[q * 16 + 11], h2.w);
      dot2a(a0, wg[q * 16 + 12], h3.x); dot2a(a1, wg[q * 16 + 13], h3.y);
      dot2a(a2, wg[q * 16 + 14], h3.z); dot2a(a3, wg[q * 16 + 15], h3.w);
    }
    float a = (a0 + a1) + (a2 + a3) + h2f(gA);
    float g = 1.f / (1.f + __expf(-a));
    if (t < 128) {
      float rgh = g * hF[t];
      float rh2 = __shfl_down(rgh, 1);
      if (!(t & 1)) rghP[t >> 1] = pkf16(rgh, rh2);
    } else {
      uF[t - 128] = g;
    }
    gbar();

    // ---- candidate + update
    float c0 = 0.f, c1 = 0.f;
    const uint4* rp = (const uint4*)&rghP[(t & 1) * 32];
#pragma unroll
    for (int q = 0; q < 8; q++) {
      uint4 rq = rp[q];
      dot2a(c0, wc[q * 4 + 0], rq.x);
      dot2a(c1, wc[q * 4 + 1], rq.y);
      dot2a(c0, wc[q * 4 + 2], rq.z);
      dot2a(c1, wc[q * 4 + 3], rq.w);
    }
    float c = c0 + c1;
    c += __shfl_xor(c, 1);
    c += h2f(cA);
    c = fminf(fmaxf(c, -15.f), 15.f);
    float e2 = __expf(2.f * c);
    c = 1.f - 2.f / (e2 + 1.f);          // tanh
    float u = uF[jc];
    if (AUGRU) u *= (1.f - alA);
    float h = hF[jc];
    float hn = u * h + (1.f - u) * c;
    float hnHi = __shfl_down(hn, 2);
    if (!(t & 1)) {
      hF[jc] = hn;
      if (!AUGRU) P.outbf[((size_t)(P.tbase + ts) * 512 + r) * 128 + jc] = f2bf(hn);
    }
    if (!(t & 3)) hH[t >> 2] = pkf16(hn, hnHi);
    gbar();

    gA = gB; cA = cB; alA = alB;
    gB = gC; cB = cC; alB = alC;
  }

  if (t < 128) P.hstate[r * 128 + t] = hF[t];
  if (!AUGRU && nsteps < TC && t < 64) {
    for (int s = nsteps; s < TC; s++)
      ((unsigned int*)(P.outbf + ((size_t)(P.tbase + s) * 512 + r) * 128))[t] = 0;
  }
}

// ---------------------------------------------------------------- his_sum body
__device__ void hsum_body(const float* __restrict__ his, float* __restrict__ hs,
                          const int* __restrict__ seqlen, int b, char* smem) {
  float* sm = (float*)smem;
  int t = threadIdx.x;
  int len = seqlen[b];
  int col = t & 127, hf = t >> 7;
  float s = 0.f;
  for (int ts = hf; ts < len; ts += 2) s += his[((size_t)b * 200 + ts) * 128 + col];
  sm[t] = s;
  __syncthreads();
  if (t < 128) hs[b * 128 + t] = sm[t] + sm[t + 128];
}

// ---------------------------------------------------------------- fat kernel
template <int AUG, int GRU, int S1, int E1, int S2, int E2, int S3, int E3, int HS>
__global__ __launch_bounds__(256) void fatk(GruP gp, GemmP p1, int c1,
                                            GemmP p2, int c2, GemmP p3,
                                            const float* hisp, float* hsp)
{
  extern __shared__ char smem[];
  int id = blockIdx.x;
  if constexpr (GRU) {
    if (id < 512) { gru_body<AUG>(gp, id, smem); return; }
    id -= 512;
  }
  if constexpr (HS) {
    if (id < 512) { hsum_body(hisp, hsp, gp.seqlen, id, smem); return; }
    id -= 512;
  }
  if constexpr (S1 >= 0) {
    if (id < c1) { gemm_body<S1, E1>(p1, id, smem); return; }
    id -= c1;
  }
  if constexpr (S2 >= 0) {
    if (id < c2) { gemm_body<S2, E2>(p2, id, smem); return; }
    id -= c2;
  }
  if constexpr (S3 >= 0) gemm_body<S3, E3>(p3, id, smem);
}

// ---------------------------------------------------------------- masked softmax (+zero hstate)
__global__ __launch_bounds__(256) void mask_softmax(
    const float* __restrict__ scores, const int* __restrict__ seqlen,
    float* __restrict__ alphas, float* __restrict__ hstate)
{
  int b = blockIdx.x, t = threadIdx.x;
  __shared__ float red[256];
  if (t < 128) hstate[b * 128 + t] = 0.f;
  int len = seqlen[b];
  float s = (t < 200 && t < len) ? scores[b * 200 + t] : -1e30f;
  red[t] = s;
  __syncthreads();
  for (int o = 128; o > 0; o >>= 1) {
    if (t < o) red[t] = fmaxf(red[t], red[t + o]);
    __syncthreads();
  }
  float m = red[0];
  __syncthreads();
  float e = (t < 200 && t < len) ? __expf(s - m) : 0.f;
  red[t] = e;
  __syncthreads();
  for (int o = 128; o > 0; o >>= 1) {
    if (t < o) red[t] += red[t + o];
    __syncthreads();
  }
  float denom = red[0];
  if (t < 200) alphas[b * 200 + t] = e / denom;
}

// ---------------------------------------------------------------- head (his_sum precomputed)
__global__ __launch_bounds__(256) void head_kernel(
    const float* __restrict__ item_eb, const float* __restrict__ hs,
    const float* __restrict__ hstate,
    const float* __restrict__ w1, const float* __restrict__ b1, const float* __restrict__ a1,
    const float* __restrict__ w2, const float* __restrict__ b2, const float* __restrict__ a2,
    const float* __restrict__ w3, const float* __restrict__ b3,
    float* __restrict__ out)
{
  int b = blockIdx.x, t = threadIdx.x;
  __shared__ float frow[512];
  __shared__ float z1[200];
  __shared__ float z2[80];
  if (t < 128) {
    float sv = hs[b * 128 + t];
    float q = item_eb[b * 128 + t];
    frow[t] = q;
    frow[128 + t] = sv;
    frow[256 + t] = q * sv;
    frow[384 + t] = hstate[b * 128 + t];
  }
  __syncthreads();
  if (t < 200) {
    float acc = b1[t];
#pragma unroll 8
    for (int k = 0; k < 512; k++) acc += frow[k] * w1[k * 200 + t];
    z1[t] = acc > 0.f ? acc : a1[t] * acc;
  }
  __syncthreads();
  if (t < 80) {
    float acc = b2[t];
#pragma unroll 8
    for (int k = 0; k < 200; k++) acc += z1[k] * w2[k * 80 + t];
    z2[t] = acc > 0.f ? acc : a2[t] * acc;
  }
  __syncthreads();
  if (t == 0) {
    float l0 = b3[0], l1 = b3[1];
    for (int k = 0; k < 80; k++) {
      float z = z2[k];
      l0 += z * w3[k * 2];
      l1 += z * w3[k * 2 + 1];
    }
    float m = fmaxf(l0, l1);
    float e0 = __expf(l0 - m), e1 = __expf(l1 - m);
    out[b * 2 + 0] = e0 / (e0 + e1);
    out[b * 2 + 1] = e1 / (e0 + e1);
  }
}

// ---------------------------------------------------------------- launch
extern "C" void kernel_launch(void* const* d_in, const int* in_sizes, int n_in,
                              void* d_out, int out_size, void* d_ws, size_t ws_size,
                              hipStream_t stream)
{
  const float* item_eb = (const float*)d_in[0];
  const float* his     = (const float*)d_in[1];
  const float* Wg1     = (const float*)d_in[2];
  const float* bg1     = (const float*)d_in[3];
  const float* Wc1     = (const float*)d_in[4];
  const float* bc1     = (const float*)d_in[5];
  const float* aw1     = (const float*)d_in[6];
  const float* ab1     = (const float*)d_in[7];
  const float* aw2     = (const float*)d_in[8];
  const float* ab2     = (const float*)d_in[9];
  const float* aw3     = (const float*)d_in[10];
  const float* ab3     = (const float*)d_in[11];
  const float* Wg2     = (const float*)d_in[12];
  const float* bg2     = (const float*)d_in[13];
  const float* Wc2     = (const float*)d_in[14];
  const float* bc2     = (const float*)d_in[15];
  const float* fc1w    = (const float*)d_in[16];
  const float* fc1b    = (const float*)d_in[17];
  const float* al1     = (const float*)d_in[18];
  const float* fc2w    = (const float*)d_in[19];
  const float* fc2b    = (const float*)d_in[20];
  const float* al2     = (const float*)d_in[21];
  const float* fc3w    = (const float*)d_in[22];
  const float* fc3b    = (const float*)d_in[23];
  const int*   seqlen  = (const int*)d_in[24];

  // ---- workspace layout (~93.5 MB; round-2 proved >=94.24 MB available)
  char* ws = (char*)d_ws;
  unsigned short* XhA    = (unsigned short*)(ws + 0L);         // 26,214,400 his bf16 t-major; later h1 ring
  unsigned short* xpA    = (unsigned short*)(ws + 26214400L);  // 19,660,800 f16 xproj buf A
  unsigned short* xpB    = (unsigned short*)(ws + 45875200L);  // 19,660,800 f16 xproj buf B
  unsigned short* rnn1   = (unsigned short*)(ws + 65536000L);  // 26,214,400
  float*          scores = (float*)(ws + 91750400L);           //    409,600 (hs after softmax)
  float*          alphas = (float*)(ws + 92160000L);           //    409,600
  float*          hstate = (float*)(ws + 92569600L);           //    262,144
  unsigned int*   WgP1   = (unsigned int*)(ws + 92831744L);    //     65,536
  unsigned int*   WcP1   = (unsigned int*)(ws + 92897280L);    //     32,768
  unsigned int*   WgP2   = (unsigned int*)(ws + 92930048L);    //     65,536
  unsigned int*   WcP2   = (unsigned int*)(ws + 92995584L);    //     32,768
  unsigned short* W1xT   = (unsigned short*)(ws + 93028352L);  //     98,304
  unsigned short* W2xT   = (unsigned short*)(ws + 93126656L);  //     98,304
  unsigned short* AW1T   = (unsigned short*)(ws + 93224960L);  //    131,072
  unsigned short* AW2T   = (unsigned short*)(ws + 93356032L);  //     32,768
  float*          b384_1 = (float*)(ws + 93388800L);           //      1,536
  float*          b384_2 = (float*)(ws + 93390336L);           //      1,536
  float*          bA1    = (float*)(ws + 93391872L);           //        512
  float*          bA2    = (float*)(ws + 93392384L);           //        512
  float*          w3p    = (float*)(ws + 93392896L);           //        512
  unsigned short* Xq     = (unsigned short*)(ws + 93393408L);  //    131,072
  float*          hs     = scores;                             // reuse after softmax

  unsigned short* h1[NC] = {XhA, XhA + CSH, XhA + 2 * CSH, XhA + 3 * CSH};

  const int SM = 32768;
  GruP gz{}; GemmP dz{};
  gz.seqlen = seqlen;

  auto mkGru = [&](int c, int aug) {
    GruP g;
    g.xproj = (c & 1) ? xpB : xpA;
    g.WgP = aug ? WgP2 : WgP1; g.WcP = aug ? WcP2 : WcP1;
    g.seqlen = seqlen; g.alphas = alphas;
    g.outbf = aug ? nullptr : rnn1; g.hstate = hstate; g.tbase = c * TC;
    return g;
  };
  auto mkXp = [&](const unsigned short* A, const float* bias, unsigned short* outp) {
    GemmP p{}; p.A = A; p.B = (bias == b384_1) ? W1xT : W2xT; p.bias = bias;
    p.out = outp; p.K = 128; p.ldc = 384; p.mtiles = 200; return p;
  };
  auto mkAtt1 = [&](int c) {
    GemmP p{}; p.B = AW1T; p.bias = bA1; p.out = h1[c];
    p.Xq = Xq; p.rnn1 = rnn1; p.rowbase = (long)c * CROWS;
    p.K = 512; p.ldc = 128; p.mtiles = 200; return p;
  };
  auto mkAtt2 = [&](int c) {
    GemmP p{}; p.A = h1[c]; p.B = AW2T; p.bias = bA2;
    p.scores = scores; p.w3p = w3p; p.b3 = ab3;
    p.K = 128; p.ldc = 128; p.mtiles = 200; p.tbase = c * TC; return p;
  };

  // L1/L2: prep + cast
  prep_weights<<<256, 256, 0, stream>>>(item_eb, Wg1, Wc1, Wg2, Wc2, aw1, aw2, aw3,
                                        bg1, bc1, bg2, bc2, ab1, ab2,
                                        W1xT, W2xT, AW1T, AW2T, b384_1, b384_2, bA1, bA2,
                                        WgP1, WcP1, WgP2, WcP2, w3p, Xq, hstate);
  cast_his_t<<<12800, 256, 0, stream>>>((const float4*)his, (ushort4*)XhA);

  // L3: xproj1-c0 -> xpA
  fatk<0,0, 0,0, -1,0, -1,0, 0><<<600, 256, SM, stream>>>(
      gz, mkXp(XhA, b384_1, xpA), 600, dz, 0, dz, nullptr, nullptr);
  // L4: gru1-c0 | xproj1-c1 -> xpB
  fatk<0,1, 0,0, -1,0, -1,0, 0><<<1112, 256, SM, stream>>>(
      mkGru(0,0), mkXp(XhA + (size_t)CSH, b384_1, xpB), 600, dz, 0, dz, nullptr, nullptr);
  // L5: gru1-c1 | xproj1-c2 -> xpA
  fatk<0,1, 0,0, -1,0, -1,0, 0><<<1112, 256, SM, stream>>>(
      mkGru(1,0), mkXp(XhA + (size_t)2*CSH, b384_1, xpA), 600, dz, 0, dz, nullptr, nullptr);
  // L6: gru1-c2 | xproj1-c3 -> xpB | att1-c0 -> h1[0]
  fatk<0,1, 0,0, 1,1, -1,0, 0><<<1712, 256, SM, stream>>>(
      mkGru(2,0), mkXp(XhA + (size_t)3*CSH, b384_1, xpB), 600, mkAtt1(0), 200, dz, nullptr, nullptr);
  // L7: gru1-c3 | att1-c1 | att2-c0
  fatk<0,1, 1,1, 0,2, -1,0, 0><<<912, 256, SM, stream>>>(
      mkGru(3,0), mkAtt1(1), 200, mkAtt2(0), 200, dz, nullptr, nullptr);
  // L8: att1-c2 | att2-c1 | augru-gemm-c0 -> xpA
  fatk<0,0, 1,1, 0,2, 0,0, 0><<<1000, 256, SM, stream>>>(
      gz, mkAtt1(2), 200, mkAtt2(1), 200, mkXp(rnn1, b384_2, xpA), nullptr, nullptr);
  // L9: att1-c3 | att2-c2 | augru-gemm-c1 -> xpB
  fatk<0,0, 1,1, 0,2, 0,0, 0><<<1000, 256, SM, stream>>>(
      gz, mkAtt1(3), 200, mkAtt2(2), 200, mkXp(rnn1 + (size_t)CSH, b384_2, xpB), nullptr, nullptr);
  // L10: att2-c3
  fatk<0,0, 0,2, -1,0, -1,0, 0><<<200, 256, SM, stream>>>(
      gz, mkAtt2(3), 200, dz, 0, dz, nullptr, nullptr);
  // L11: softmax + zero hstate
  mask_softmax<<<512, 256, 0, stream>>>(scores, seqlen, alphas, hstate);
  // L12: augru-c0 | his_sum backfill
  fatk<1,1, -1,0, -1,0, -1,0, 1><<<1024, 256, SM, stream>>>(
      mkGru(0,1), dz, 0, dz, 0, dz, his, hs);
  // L13: augru-c1 | augru-gemm-c2 -> xpA
  fatk<1,1, 0,0, -1,0, -1,0, 0><<<1112, 256, SM, stream>>>(
      mkGru(1,1), mkXp(rnn1 + (size_t)2*CSH, b384_2, xpA), 600, dz, 0, dz, nullptr, nullptr);
  // L14: augru-c2 | augru-gemm-c3 -> xpB
  fatk<1,1, 0,0, -1,0, -1,0, 0><<<1112, 256, SM, stream>>>(
      mkGru(2,1), mkXp(rnn1 + (size_t)3*CSH, b384_2, xpB), 600, dz, 0, dz, nullptr, nullptr);
  // L15: augru-c3
  fatk<1,1, -1,0, -1,0, -1,0, 0><<<512, 256, SM, stream>>>(
      mkGru(3,1), dz, 0, dz, 0, dz, nullptr, nullptr);
  // L16: head
  head_kernel<<<512, 256, 0, stream>>>(item_eb, hs, hstate,
                                       fc1w, fc1b, al1, fc2w, fc2b, al2,
                                       fc3w, fc3b, (float*)d_out);
}